// Round 3
// baseline (6164.431 us; speedup 1.0000x reference)
//
#include <hip/hip_runtime.h>
#include <cstddef>

// ---------------------------------------------------------------------------
// Problem constants
//   x: (32, 3, 2048) fp32
//   layer1: C=3,  CO2=32,  CO=64,  K=16, N=2048
//   fps -> 512 points; gather x1
//   layer2: C=64, CO2=128, CO=256, K=8,  N=512
//   layer3: C=256,CO2=256, CO=512, K=4,  N=512
//   out: (32, 64+256+512=832, 512) fp32
//
// All discrete selections (knn top-k, fps argmax) are computed in fp64:
// fp32 inputs -> fp64 products exact -> true ordering, minimizing
// boundary-tie disagreement vs the reference.
// ---------------------------------------------------------------------------

// ---------------- workspace layout (in float units) ----------------
constexpr size_t OFF_IDX1 = 0;                         // int[32*2048*16]
constexpr size_t OFF_IDX2 = OFF_IDX1 + 1048576;        // int[32*512*8]
constexpr size_t OFF_IDX3 = OFF_IDX2 + 131072;         // int[32*512*4]
constexpr size_t OFF_FPS  = OFF_IDX3 + 65536;          // int[32*512]
constexpr size_t OFF_ST   = OFF_FPS + 16384;           // double[832] = 1664 floats (st1|st2|st3)
constexpr size_t OFF_SS1  = OFF_ST + 1664;             // float[64]
constexpr size_t OFF_SS2  = OFF_SS1 + 64;              // float[256]
constexpr size_t OFF_SS3  = OFF_SS2 + 256;             // float[512]
constexpr size_t OFF_NORM = OFF_SS3 + 512;             // double[32*512] = 32768 floats
constexpr size_t OFF_X1F  = OFF_NORM + 32768;          // float[32*2048*64] (B,N,C layout)

// ---------------------------------------------------------------------------
// kNN for layer 1 (C=3, N=2048, K=16).  One thread per query; fp64 distances.
// ---------------------------------------------------------------------------
__global__ __launch_bounds__(256) void knn3d_kernel(const float* __restrict__ x,
                                                    int* __restrict__ idx)
{
    constexpr int N = 2048;
    __shared__ double sxd[256], syd[256], szd[256], snd[256];
    int b = blockIdx.x >> 3;
    int n = ((blockIdx.x & 7) << 8) + threadIdx.x;
    const float* xb = x + (size_t)b * 3 * N;
    double qx = (double)xb[n], qy = (double)xb[N + n], qz = (double)xb[2 * N + n];
    double qq = qx * qx + qy * qy + qz * qz;
    double bv[16]; int bi[16];
#pragma unroll
    for (int j = 0; j < 16; j++) { bv[j] = -1e300; bi[j] = 0; }

    for (int t0 = 0; t0 < N; t0 += 256) {
        __syncthreads();
        int mi = t0 + threadIdx.x;
        double mx = (double)xb[mi], my = (double)xb[N + mi], mz = (double)xb[2 * N + mi];
        sxd[threadIdx.x] = mx; syd[threadIdx.x] = my; szd[threadIdx.x] = mz;
        snd[threadIdx.x] = mx * mx + my * my + mz * mz;
        __syncthreads();
        for (int mm = 0; mm < 256; mm++) {
            double dot = qx * sxd[mm] + qy * syd[mm] + qz * szd[mm];
            double val = 2.0 * dot - qq - snd[mm];
            if (val > bv[15]) {
                bv[15] = val; bi[15] = t0 + mm;
#pragma unroll
                for (int j = 15; j > 0; j--) {
                    if (bv[j] > bv[j - 1]) {
                        double tv = bv[j]; bv[j] = bv[j - 1]; bv[j - 1] = tv;
                        int    ti = bi[j]; bi[j] = bi[j - 1]; bi[j - 1] = ti;
                    }
                }
            }
        }
    }
    int* op = idx + ((size_t)(b * N) + n) * 16;
#pragma unroll
    for (int j = 0; j < 16; j++) op[j] = bi[j];
}

// ---------------------------------------------------------------------------
// Layer-1 BN statistics (per-thread fp32 partials, fp64 atomics)
// ---------------------------------------------------------------------------
__global__ __launch_bounds__(256) void stats1_kernel(const float* __restrict__ x,
                                                     const int* __restrict__ idx1,
                                                     const float* __restrict__ w1,
                                                     const float* __restrict__ b1,
                                                     double* __restrict__ stats)
{
    __shared__ float wl[32][9];
    __shared__ float bsh[32];
    __shared__ float red[2][4][32];
    int t = threadIdx.x;
    for (int e = t; e < 192; e += 256) wl[e / 6][e % 6] = w1[e];
    if (t < 32) bsh[t] = b1[t];
    __syncthreads();

    float sum[32], sq[32];
#pragma unroll
    for (int o = 0; o < 32; o++) { sum[o] = 0.f; sq[o] = 0.f; }

    int base = blockIdx.x * 256 + t;
    for (int it = 0; it < 16; ++it) {
        int p = base + it * 65536;          // p < 2^20
        int b = p >> 15, rem = p & 32767, n = rem >> 4;
        int m = idx1[p];
        const float* xb = x + (size_t)b * 3 * 2048;
        float cx = xb[n], cy = xb[2048 + n], cz = xb[4096 + n];
        float f0 = cx - xb[m], f1 = cy - xb[2048 + m], f2 = cz - xb[4096 + m];
#pragma unroll
        for (int o = 0; o < 32; o++) {
            float h = bsh[o] + wl[o][0] * f0 + wl[o][1] * f1 + wl[o][2] * f2
                             + wl[o][3] * cx + wl[o][4] * cy + wl[o][5] * cz;
            sum[o] += h; sq[o] += h * h;
        }
    }
    int lane = t & 63, wv = t >> 6;
#pragma unroll
    for (int o = 0; o < 32; o++) {
        float s = sum[o], q = sq[o];
#pragma unroll
        for (int d = 1; d < 64; d <<= 1) { s += __shfl_xor(s, d); q += __shfl_xor(q, d); }
        if (lane == 0) { red[0][wv][o] = s; red[1][wv][o] = q; }
    }
    __syncthreads();
    if (t < 32) {
        atomicAdd(&stats[t], (double)(red[0][0][t] + red[0][1][t] + red[0][2][t] + red[0][3][t]));
    } else if (t < 64) {
        int o = t - 32;
        atomicAdd(&stats[32 + o], (double)(red[1][0][o] + red[1][1][o] + red[1][2][o] + red[1][3][o]));
    }
}

// ---------------------------------------------------------------------------
// scale/shift from (sum, sumsq) in fp64
// ---------------------------------------------------------------------------
__global__ void finalize_kernel(const double* __restrict__ stats,
                                const float* __restrict__ g,
                                const float* __restrict__ be,
                                float* __restrict__ scsh, int co2, double invcnt)
{
    int t = threadIdx.x;
    if (t < co2) {
        double mu  = stats[t] * invcnt;
        double var = stats[co2 + t] * invcnt - mu * mu;
        float  sc  = (float)((double)g[t] / sqrt(var + 1e-5));
        scsh[t]       = sc;
        scsh[co2 + t] = be[t] - (float)mu * sc;
    }
}

// ---------------------------------------------------------------------------
// Layer-1 pass B
// ---------------------------------------------------------------------------
__global__ __launch_bounds__(256) void passB1_kernel(const float* __restrict__ x,
                                                     const int* __restrict__ idx1,
                                                     const float* __restrict__ w1,
                                                     const float* __restrict__ b1,
                                                     const float* __restrict__ scsh,
                                                     const float* __restrict__ w2,
                                                     const float* __restrict__ b2,
                                                     float* __restrict__ x1full)
{
    __shared__ float hn[256][36];
    __shared__ float wl[32][9];
    __shared__ float sc[32], sh[32], bs1[32];
    int t = threadIdx.x;
    int b = blockIdx.x >> 7, nt = blockIdx.x & 127;
    int n0 = nt << 4;
    for (int e = t; e < 192; e += 256) wl[e / 6][e % 6] = w1[e];
    if (t < 32) { sc[t] = scsh[t]; sh[t] = scsh[32 + t]; bs1[t] = b1[t]; }
    __syncthreads();
    {
        int n = n0 + (t >> 4), kk = t & 15;
        int pix = (((b << 11) + n) << 4) + kk;
        int m = idx1[pix];
        const float* xb = x + (size_t)b * 3 * 2048;
        float cx = xb[n], cy = xb[2048 + n], cz = xb[4096 + n];
        float f0 = cx - xb[m], f1 = cy - xb[2048 + m], f2 = cz - xb[4096 + m];
#pragma unroll
        for (int o = 0; o < 32; o++) {
            float h = bs1[o] + wl[o][0] * f0 + wl[o][1] * f1 + wl[o][2] * f2
                             + wl[o][3] * cx + wl[o][4] * cy + wl[o][5] * cz;
            h = h * sc[o] + sh[o];
            hn[t][o] = (h >= 0.f) ? h : 0.2f * h;
        }
    }
    __syncthreads();
    int o2 = t & 63, ng = t >> 6;
    float w2r[32];
#pragma unroll
    for (int c = 0; c < 32; c++) w2r[c] = w2[o2 * 32 + c];
    float bb = b2[o2];
#pragma unroll
    for (int ns = 0; ns < 4; ns++) {
        int nl = ng * 4 + ns;
        float mx = -1e30f;
#pragma unroll
        for (int kk = 0; kk < 16; kk++) {
            const float* hp = &hn[(nl << 4) + kk][0];
            float s = 0.f;
#pragma unroll
            for (int c4 = 0; c4 < 8; c4++) {
                float4 f = *(const float4*)(hp + c4 * 4);
                s += w2r[c4 * 4] * f.x + w2r[c4 * 4 + 1] * f.y
                   + w2r[c4 * 4 + 2] * f.z + w2r[c4 * 4 + 3] * f.w;
            }
            mx = fmaxf(mx, s);
        }
        x1full[((size_t)(b << 11) + n0 + nl) * 64 + o2] = mx + bb;
    }
}

// ---------------------------------------------------------------------------
// Farthest point sampling — distances in fp64 (exact for fp32 inputs).
// ---------------------------------------------------------------------------
__global__ __launch_bounds__(64) void fps_kernel(const float* __restrict__ x,
                                                 int* __restrict__ fpsidx)
{
    int b = blockIdx.x, l = threadIdx.x;
    const float* xb = x + (size_t)b * 3 * 2048;
    __shared__ float sx[2048], sy[2048], sz[2048];
    float px[32], py[32], pz[32];
    double dd[32];
#pragma unroll
    for (int j = 0; j < 32; j++) {
        int n = j * 64 + l;
        float a = xb[n], bb2 = xb[2048 + n], c = xb[4096 + n];
        px[j] = a; py[j] = bb2; pz[j] = c; dd[j] = 1e30;
        sx[n] = a; sy[n] = bb2; sz[n] = c;
    }
    __syncthreads();
    if (l == 0) fpsidx[(size_t)b * 512] = 0;
    int last = 0;
    for (int i = 1; i < 512; i++) {
        double lpx = (double)sx[last], lpy = (double)sy[last], lpz = (double)sz[last];
        double bestd = -1.0; int bestn = 0;
#pragma unroll
        for (int j = 0; j < 32; j++) {
            double dx = (double)px[j] - lpx, dy = (double)py[j] - lpy, dz = (double)pz[j] - lpz;
            double d = dx * dx + dy * dy + dz * dz;
            double nd = fmin(dd[j], d);
            dd[j] = nd;
            if (nd > bestd) { bestd = nd; bestn = j * 64 + l; }
        }
#pragma unroll
        for (int s = 1; s < 64; s <<= 1) {
            double od = __shfl_xor(bestd, s);
            int    on = __shfl_xor(bestn, s);
            if (od > bestd || (od == bestd && on < bestn)) { bestd = od; bestn = on; }
        }
        last = bestn;
        if (l == 0) fpsidx[(size_t)b * 512 + i] = bestn;
    }
}

// ---------------------------------------------------------------------------
// Gather x1 at fps indices into d_out channels [0,64).
// ---------------------------------------------------------------------------
__global__ __launch_bounds__(256) void gather_kernel(const float* __restrict__ x1full,
                                                     const int* __restrict__ fpsidx,
                                                     float* __restrict__ out)
{
    int e = blockIdx.x * 256 + threadIdx.x;   // < 32*64*512
    int j = e & 511; int rest = e >> 9; int c = rest & 63; int b = rest >> 6;
    int fj = fpsidx[b * 512 + j];
    out[((size_t)b * 832 + c) * 512 + j] = x1full[((size_t)(b << 11) + fj) * 64 + c];
}

// ---------------------------------------------------------------------------
// Squared norms per point (fp64) for a (B, C, 512) channel-major array.
// ---------------------------------------------------------------------------
template <int C>
__global__ __launch_bounds__(256) void norms_kernel(const float* __restrict__ xin,
                                                    size_t xbstride,
                                                    double* __restrict__ norms)
{
    int b = blockIdx.x >> 1;
    int n = ((blockIdx.x & 1) << 8) + threadIdx.x;
    const float* xb = xin + (size_t)b * xbstride;
    double s = 0.0;
    for (int c = 0; c < C; c++) { double v = (double)xb[(size_t)c * 512 + n]; s += v * v; }
    norms[(b << 9) + n] = s;
}

// ---------------------------------------------------------------------------
// kNN for feature layers (N=512), fp64 distance accumulation.
// ---------------------------------------------------------------------------
template <int C, int KK, int MT>
__global__ __launch_bounds__(256) void knn_feat_kernel(const float* __restrict__ xin,
                                                       size_t xbstride,
                                                       const double* __restrict__ norms,
                                                       int* __restrict__ idxout)
{
    constexpr int NN = 512;
    __shared__ float sm[MT][C + 4];
    __shared__ double smn[MT];
    int b = blockIdx.x >> 1;
    int n = ((blockIdx.x & 1) << 8) + threadIdx.x;
    const float* xb = xin + (size_t)b * xbstride;
    double qq = norms[(b << 9) + n];
    double bv[KK]; int bi[KK];
#pragma unroll
    for (int j = 0; j < KK; j++) { bv[j] = -1e300; bi[j] = 0; }

    for (int t0 = 0; t0 < NN; t0 += MT) {
        __syncthreads();
        for (int e = threadIdx.x; e < MT * C; e += 256) {
            int mm = e % MT, c = e / MT;
            sm[mm][c] = xb[(size_t)c * NN + t0 + mm];
        }
        if (threadIdx.x < MT) smn[threadIdx.x] = norms[(b << 9) + t0 + threadIdx.x];
        __syncthreads();
        double acc[MT];
#pragma unroll
        for (int mm = 0; mm < MT; mm++) acc[mm] = 0.0;
        for (int c0 = 0; c0 < C; c0 += 8) {
            double q0 = (double)xb[(size_t)(c0 + 0) * NN + n], q1 = (double)xb[(size_t)(c0 + 1) * NN + n];
            double q2 = (double)xb[(size_t)(c0 + 2) * NN + n], q3 = (double)xb[(size_t)(c0 + 3) * NN + n];
            double q4 = (double)xb[(size_t)(c0 + 4) * NN + n], q5 = (double)xb[(size_t)(c0 + 5) * NN + n];
            double q6 = (double)xb[(size_t)(c0 + 6) * NN + n], q7 = (double)xb[(size_t)(c0 + 7) * NN + n];
#pragma unroll
            for (int mm = 0; mm < MT; mm++) {
                float4 f0 = *(const float4*)&sm[mm][c0];
                float4 f1 = *(const float4*)&sm[mm][c0 + 4];
                acc[mm] += q0 * (double)f0.x + q1 * (double)f0.y + q2 * (double)f0.z + q3 * (double)f0.w
                         + q4 * (double)f1.x + q5 * (double)f1.y + q6 * (double)f1.z + q7 * (double)f1.w;
            }
        }
#pragma unroll
        for (int mm = 0; mm < MT; mm++) {
            double val = 2.0 * acc[mm] - qq - smn[mm];
            if (val > bv[KK - 1]) {
                bv[KK - 1] = val; bi[KK - 1] = t0 + mm;
#pragma unroll
                for (int j = KK - 1; j > 0; j--) {
                    if (bv[j] > bv[j - 1]) {
                        double tv = bv[j]; bv[j] = bv[j - 1]; bv[j - 1] = tv;
                        int    tn = bi[j]; bi[j] = bi[j - 1]; bi[j - 1] = tn;
                    }
                }
            }
        }
    }
    int* op = idxout + ((size_t)(b * NN) + n) * KK;
#pragma unroll
    for (int j = 0; j < KK; j++) op[j] = bi[j];
}

// ---------------------------------------------------------------------------
// Generic edge-conv kernel for layers 2/3.
// ---------------------------------------------------------------------------
template <int C, int CO2, int KK, bool STATS>
__global__ __launch_bounds__(CO2) void edge_kernel(
    const float* __restrict__ xin, size_t xbstride, const int* __restrict__ idx,
    const float* __restrict__ w1, const float* __restrict__ b1,
    double* __restrict__ stats,
    const float* __restrict__ scsh, const float* __restrict__ w2,
    const float* __restrict__ b2,
    float* __restrict__ outp, size_t obstride, int tiles_per_block)
{
    constexpr int NN = 512, C2 = 2 * C, CCH = 16, TP = 32, TN = TP / KK;
    constexpr int CHUNKS = C2 / CCH;
    __shared__ float featc[TP][CCH + 4];
    __shared__ float wtl[CCH][CO2 + 1];
    __shared__ float hn[STATS ? 1 : TP * CO2];
    __shared__ int   smidx[TP];
    int t = threadIdx.x;
    float ssum = 0.f, ssq = 0.f;
    float bb1 = b1[t];

    for (int ti = 0; ti < tiles_per_block; ++ti) {
        int tileIdx = blockIdx.x * tiles_per_block + ti;
        int b = tileIdx / (NN / TN), nt = tileIdx % (NN / TN);
        int n0 = nt * TN;
        const float* xb = xin + (size_t)b * xbstride;
        if (t < TP) {
            int p = t, n = n0 + p / KK, kk = p % KK;
            smidx[p] = idx[((size_t)(b * NN) + n) * KK + kk];
        }
        float h[TP];
#pragma unroll
        for (int p = 0; p < TP; p++) h[p] = bb1;

        for (int ch = 0; ch < CHUNKS; ++ch) {
            int c0 = ch * CCH;
            __syncthreads();
            for (int e = t; e < TP * CCH; e += CO2) {
                int p = e & (TP - 1), ci = e >> 5;
                int c = c0 + ci;
                int n = n0 + p / KK;
                int m = smidx[p];
                float v = (c < C) ? (xb[(size_t)c * NN + n] - xb[(size_t)c * NN + m])
                                  : xb[(size_t)(c - C) * NN + n];
                featc[p][ci] = v;
            }
            for (int e = t; e < CCH * CO2; e += CO2) {
                int o = e / CCH, ci = e % CCH;
                wtl[ci][o] = w1[(size_t)o * C2 + c0 + ci];
            }
            __syncthreads();
#pragma unroll
            for (int c4 = 0; c4 < CCH / 4; c4++) {
                float a0 = wtl[c4 * 4][t], a1 = wtl[c4 * 4 + 1][t];
                float a2 = wtl[c4 * 4 + 2][t], a3 = wtl[c4 * 4 + 3][t];
#pragma unroll
                for (int p = 0; p < TP; p++) {
                    float4 f = *(const float4*)&featc[p][c4 * 4];
                    h[p] += a0 * f.x + a1 * f.y + a2 * f.z + a3 * f.w;
                }
            }
        }
        if constexpr (STATS) {
#pragma unroll
            for (int p = 0; p < TP; p++) { ssum += h[p]; ssq += h[p] * h[p]; }
        } else {
            float scv = scsh[t], shv = scsh[CO2 + t];
#pragma unroll
            for (int p = 0; p < TP; p++) {
                float v = h[p] * scv + shv;
                hn[p * CO2 + t] = (v >= 0.f) ? v : 0.2f * v;
            }
            for (int g = 0; g < 2; ++g) {
                float s[TP];
#pragma unroll
                for (int p = 0; p < TP; p++) s[p] = 0.f;
                for (int ch = 0; ch < CO2 / CCH; ++ch) {
                    int c0 = ch * CCH;
                    __syncthreads();
                    for (int e = t; e < CCH * CO2; e += CO2) {
                        int o = e / CCH, ci = e % CCH;
                        wtl[ci][o] = w2[((size_t)(g * CO2 + o)) * CO2 + c0 + ci];
                    }
                    __syncthreads();
#pragma unroll
                    for (int c4 = 0; c4 < CCH / 4; c4++) {
                        float a0 = wtl[c4 * 4][t], a1 = wtl[c4 * 4 + 1][t];
                        float a2 = wtl[c4 * 4 + 2][t], a3 = wtl[c4 * 4 + 3][t];
#pragma unroll
                        for (int p = 0; p < TP; p++) {
                            const float4 f = *(const float4*)&hn[p * CO2 + c0 + c4 * 4];
                            s[p] += a0 * f.x + a1 * f.y + a2 * f.z + a3 * f.w;
                        }
                    }
                }
                float bb2 = b2[g * CO2 + t];
#pragma unroll
                for (int nl = 0; nl < TN; ++nl) {
                    float mx = s[nl * KK];
#pragma unroll
                    for (int kk = 1; kk < KK; ++kk) mx = fmaxf(mx, s[nl * KK + kk]);
                    outp[(size_t)b * obstride + (size_t)(g * CO2 + t) * NN + n0 + nl] = mx + bb2;
                }
            }
        }
    }
    if constexpr (STATS) {
        atomicAdd(&stats[t], (double)ssum);
        atomicAdd(&stats[CO2 + t], (double)ssq);
    }
}

// ---------------------------------------------------------------------------
extern "C" void kernel_launch(void* const* d_in, const int* in_sizes, int n_in,
                              void* d_out, int out_size, void* d_ws, size_t ws_size,
                              hipStream_t stream)
{
    const float* x   = (const float*)d_in[0];
    const float* w1a = (const float*)d_in[1];
    const float* b1a = (const float*)d_in[2];
    const float* g1  = (const float*)d_in[3];
    const float* be1 = (const float*)d_in[4];
    const float* w1b = (const float*)d_in[5];
    const float* b1b = (const float*)d_in[6];
    const float* w2a = (const float*)d_in[7];
    const float* b2a = (const float*)d_in[8];
    const float* g2  = (const float*)d_in[9];
    const float* be2 = (const float*)d_in[10];
    const float* w2b = (const float*)d_in[11];
    const float* b2b = (const float*)d_in[12];
    const float* w3a = (const float*)d_in[13];
    const float* b3a = (const float*)d_in[14];
    const float* g3  = (const float*)d_in[15];
    const float* be3 = (const float*)d_in[16];
    const float* w3b = (const float*)d_in[17];
    const float* b3b = (const float*)d_in[18];

    float* out = (float*)d_out;
    float* fws = (float*)d_ws;
    int*    idx1   = (int*)(fws + OFF_IDX1);
    int*    idx2   = (int*)(fws + OFF_IDX2);
    int*    idx3   = (int*)(fws + OFF_IDX3);
    int*    fpsidx = (int*)(fws + OFF_FPS);
    double* st1 = (double*)(fws + OFF_ST);          // 64 doubles
    double* st2 = st1 + 64;                         // 256 doubles
    double* st3 = st2 + 256;                        // 512 doubles
    float*  ss1 = fws + OFF_SS1;
    float*  ss2 = fws + OFF_SS2;
    float*  ss3 = fws + OFF_SS3;
    double* nrm = (double*)(fws + OFF_NORM);
    float*  x1full = fws + OFF_X1F;

    const size_t OB = 832 * 512;   // per-batch stride of d_out

    // zero BN stat accumulators (832 doubles, contiguous)
    hipMemsetAsync(st1, 0, 832 * sizeof(double), stream);

    // ---- layer 1 ----
    knn3d_kernel<<<256, 256, 0, stream>>>(x, idx1);
    stats1_kernel<<<256, 256, 0, stream>>>(x, idx1, w1a, b1a, st1);
    finalize_kernel<<<1, 256, 0, stream>>>(st1, g1, be1, ss1, 32, 1.0 / 1048576.0);
    passB1_kernel<<<4096, 256, 0, stream>>>(x, idx1, w1a, b1a, ss1, w1b, b1b, x1full);

    // ---- fps + gather ----
    fps_kernel<<<32, 64, 0, stream>>>(x, fpsidx);
    gather_kernel<<<4096, 256, 0, stream>>>(x1full, fpsidx, out);

    // ---- layer 2 (input = out channels [0,64)) ----
    norms_kernel<64><<<64, 256, 0, stream>>>(out, OB, nrm);
    knn_feat_kernel<64, 8, 32><<<64, 256, 0, stream>>>(out, OB, nrm, idx2);
    edge_kernel<64, 128, 8, true><<<512, 128, 0, stream>>>(
        out, OB, idx2, w2a, b2a, st2, nullptr, nullptr, nullptr, nullptr, 0, 8);
    finalize_kernel<<<1, 256, 0, stream>>>(st2, g2, be2, ss2, 128, 1.0 / 131072.0);
    edge_kernel<64, 128, 8, false><<<4096, 128, 0, stream>>>(
        out, OB, idx2, w2a, b2a, nullptr, ss2, w2b, b2b, out + 64 * 512, OB, 1);

    // ---- layer 3 (input = out channels [64,320)) ----
    norms_kernel<256><<<64, 256, 0, stream>>>(out + 64 * 512, OB, nrm);
    knn_feat_kernel<256, 4, 32><<<64, 256, 0, stream>>>(out + 64 * 512, OB, nrm, idx3);
    edge_kernel<256, 256, 4, true><<<512, 256, 0, stream>>>(
        out + 64 * 512, OB, idx3, w3a, b3a, st3, nullptr, nullptr, nullptr, nullptr, 0, 4);
    finalize_kernel<<<1, 256, 0, stream>>>(st3, g3, be3, ss3, 256, 1.0 / 65536.0);
    edge_kernel<256, 256, 4, false><<<2048, 256, 0, stream>>>(
        out + 64 * 512, OB, idx3, w3a, b3a, nullptr, ss3, w3b, b3b, out + 320 * 512, OB, 1);
}

// Round 4
// 5460.607 us; speedup vs baseline: 1.1289x; 1.1289x over previous
//
#include <hip/hip_runtime.h>
#include <cstddef>

// ---------------------------------------------------------------------------
// Problem constants
//   x: (32, 3, 2048) fp32
//   layer1: C=3,  CO2=32,  CO=64,  K=16, N=2048
//   fps -> 512 points; gather x1
//   layer2: C=64, CO2=128, CO=256, K=8,  N=512
//   layer3: C=256,CO2=256, CO=512, K=4,  N=512
//   out: (32, 64+256+512=832, 512) fp32
//
// All discrete selections (knn top-k, fps argmax) are computed in fp64 with a
// channel-ascending accumulation order (bitwise identical to the round-3
// passing version) -> true ordering, no boundary flips vs reference.
// ---------------------------------------------------------------------------

// ---------------- workspace layout (in float units) ----------------
constexpr size_t OFF_IDX1 = 0;                         // int[32*2048*16]
constexpr size_t OFF_IDX2 = OFF_IDX1 + 1048576;        // int[32*512*8]
constexpr size_t OFF_IDX3 = OFF_IDX2 + 131072;         // int[32*512*4]
constexpr size_t OFF_FPS  = OFF_IDX3 + 65536;          // int[32*512]
constexpr size_t OFF_ST   = OFF_FPS + 16384;           // double[832] = 1664 floats
constexpr size_t OFF_SS1  = OFF_ST + 1664;             // float[64]
constexpr size_t OFF_SS2  = OFF_SS1 + 64;              // float[256]
constexpr size_t OFF_SS3  = OFF_SS2 + 256;             // float[512]
constexpr size_t OFF_NORM = OFF_SS3 + 512;             // double[32*512] = 32768 floats
constexpr size_t OFF_X1F  = OFF_NORM + 32768;          // float[32*2048*64] (B,N,C layout)

// ---------------------------------------------------------------------------
// Layer-1 kNN (C=3, N=2048, K=16), query x slice decomposition.
// Block = 256 thr = 16 queries x 16 slices (128 candidates each).
// Grid = 32 b * 128 qblocks = 4096.
// ---------------------------------------------------------------------------
__global__ __launch_bounds__(256) void knn3d2_kernel(const float* __restrict__ x,
                                                     int* __restrict__ idx)
{
    constexpr int N = 2048, QB = 16, NS = 16, MS = N / NS, KK = 16;
    __shared__ __align__(16) double smem[6144];
    float*  sx  = (float*)smem;            // [2048]
    float*  sy  = (float*)(smem + 1024);   // [2048]
    float*  sz  = (float*)(smem + 2048);   // [2048]
    double* snd = smem + 3072;             // [2048]
    double* mv  = smem;                    // [QB][NS][KK]  (overlays coords, dead)
    int*    mi  = (int*)(smem + 4096);     // [QB][NS][KK]

    int t = threadIdx.x;
    int q = t & 15, s = t >> 4;
    int b  = blockIdx.x >> 7;
    int n0 = (blockIdx.x & 127) << 4;
    int n  = n0 + q;
    const float* xb = x + (size_t)b * 3 * N;

    for (int e = t; e < N; e += 256) {
        float mx = xb[e], my = xb[N + e], mz = xb[2 * N + e];
        sx[e] = mx; sy[e] = my; sz[e] = mz;
        double dx = (double)mx, dy = (double)my, dz = (double)mz;
        snd[e] = dx * dx + dy * dy + dz * dz;
    }
    __syncthreads();

    double qx = (double)sx[n], qy = (double)sy[n], qz = (double)sz[n];
    double qq = snd[n];
    double bv[KK]; int bi[KK];
#pragma unroll
    for (int j = 0; j < KK; ++j) { bv[j] = -1e300; bi[j] = 0; }

#pragma unroll 4
    for (int mm = 0; mm < MS; ++mm) {
        int m = s * MS + mm;
        double dot = qx * (double)sx[m] + qy * (double)sy[m] + qz * (double)sz[m];
        double val = 2.0 * dot - qq - snd[m];
        if (val > bv[KK - 1]) {
            bv[KK - 1] = val; bi[KK - 1] = m;
#pragma unroll
            for (int j = KK - 1; j > 0; --j) {
                if (bv[j] > bv[j - 1]) {
                    double tv = bv[j]; bv[j] = bv[j - 1]; bv[j - 1] = tv;
                    int    ti = bi[j]; bi[j] = bi[j - 1]; bi[j - 1] = ti;
                }
            }
        }
    }
    __syncthreads();   // coords/norms reads done; safe to overlay merge buffers
#pragma unroll
    for (int j = 0; j < KK; ++j) {
        mv[(q * NS + s) * KK + j] = bv[j];
        mi[(q * NS + s) * KK + j] = bi[j];
    }
    __syncthreads();
    if (t < QB) {
        int qq2 = t;
        double hv[NS]; int hj[NS];
#pragma unroll
        for (int s2 = 0; s2 < NS; ++s2) { hv[s2] = mv[(qq2 * NS + s2) * KK]; hj[s2] = 0; }
        int* op = idx + ((size_t)(b * N) + n0 + qq2) * KK;
#pragma unroll
        for (int r = 0; r < KK; ++r) {
            double best = -1e301; int bs = 0;
#pragma unroll
            for (int s2 = 0; s2 < NS; ++s2) {
                if (hv[s2] > best) { best = hv[s2]; bs = s2; }
            }
#pragma unroll
            for (int s2 = 0; s2 < NS; ++s2) {
                if (s2 == bs) {
                    op[r] = mi[(qq2 * NS + s2) * KK + hj[s2]];
                    hj[s2]++;
                    hv[s2] = (hj[s2] < KK) ? mv[(qq2 * NS + s2) * KK + hj[s2]] : -1e301;
                }
            }
        }
    }
}

// ---------------------------------------------------------------------------
// Layer-1 BN statistics
// ---------------------------------------------------------------------------
__global__ __launch_bounds__(256) void stats1_kernel(const float* __restrict__ x,
                                                     const int* __restrict__ idx1,
                                                     const float* __restrict__ w1,
                                                     const float* __restrict__ b1,
                                                     double* __restrict__ stats)
{
    __shared__ float wl[32][9];
    __shared__ float bsh[32];
    __shared__ float red[2][4][32];
    int t = threadIdx.x;
    for (int e = t; e < 192; e += 256) wl[e / 6][e % 6] = w1[e];
    if (t < 32) bsh[t] = b1[t];
    __syncthreads();

    float sum[32], sq[32];
#pragma unroll
    for (int o = 0; o < 32; o++) { sum[o] = 0.f; sq[o] = 0.f; }

    int base = blockIdx.x * 256 + t;
    for (int it = 0; it < 16; ++it) {
        int p = base + it * 65536;          // p < 2^20
        int b = p >> 15, rem = p & 32767, n = rem >> 4;
        int m = idx1[p];
        const float* xb = x + (size_t)b * 3 * 2048;
        float cx = xb[n], cy = xb[2048 + n], cz = xb[4096 + n];
        float f0 = cx - xb[m], f1 = cy - xb[2048 + m], f2 = cz - xb[4096 + m];
#pragma unroll
        for (int o = 0; o < 32; o++) {
            float h = bsh[o] + wl[o][0] * f0 + wl[o][1] * f1 + wl[o][2] * f2
                             + wl[o][3] * cx + wl[o][4] * cy + wl[o][5] * cz;
            sum[o] += h; sq[o] += h * h;
        }
    }
    int lane = t & 63, wv = t >> 6;
#pragma unroll
    for (int o = 0; o < 32; o++) {
        float s = sum[o], q = sq[o];
#pragma unroll
        for (int d = 1; d < 64; d <<= 1) { s += __shfl_xor(s, d); q += __shfl_xor(q, d); }
        if (lane == 0) { red[0][wv][o] = s; red[1][wv][o] = q; }
    }
    __syncthreads();
    if (t < 32) {
        atomicAdd(&stats[t], (double)(red[0][0][t] + red[0][1][t] + red[0][2][t] + red[0][3][t]));
    } else if (t < 64) {
        int o = t - 32;
        atomicAdd(&stats[32 + o], (double)(red[1][0][o] + red[1][1][o] + red[1][2][o] + red[1][3][o]));
    }
}

// ---------------------------------------------------------------------------
// scale/shift from (sum, sumsq) in fp64
// ---------------------------------------------------------------------------
__global__ void finalize_kernel(const double* __restrict__ stats,
                                const float* __restrict__ g,
                                const float* __restrict__ be,
                                float* __restrict__ scsh, int co2, double invcnt)
{
    int t = threadIdx.x;
    if (t < co2) {
        double mu  = stats[t] * invcnt;
        double var = stats[co2 + t] * invcnt - mu * mu;
        float  sc  = (float)((double)g[t] / sqrt(var + 1e-5));
        scsh[t]       = sc;
        scsh[co2 + t] = be[t] - (float)mu * sc;
    }
}

// ---------------------------------------------------------------------------
// Layer-1 pass B
// ---------------------------------------------------------------------------
__global__ __launch_bounds__(256) void passB1_kernel(const float* __restrict__ x,
                                                     const int* __restrict__ idx1,
                                                     const float* __restrict__ w1,
                                                     const float* __restrict__ b1,
                                                     const float* __restrict__ scsh,
                                                     const float* __restrict__ w2,
                                                     const float* __restrict__ b2,
                                                     float* __restrict__ x1full)
{
    __shared__ float hn[256][36];
    __shared__ float wl[32][9];
    __shared__ float sc[32], sh[32], bs1[32];
    int t = threadIdx.x;
    int b = blockIdx.x >> 7, nt = blockIdx.x & 127;
    int n0 = nt << 4;
    for (int e = t; e < 192; e += 256) wl[e / 6][e % 6] = w1[e];
    if (t < 32) { sc[t] = scsh[t]; sh[t] = scsh[32 + t]; bs1[t] = b1[t]; }
    __syncthreads();
    {
        int n = n0 + (t >> 4), kk = t & 15;
        int pix = (((b << 11) + n) << 4) + kk;
        int m = idx1[pix];
        const float* xb = x + (size_t)b * 3 * 2048;
        float cx = xb[n], cy = xb[2048 + n], cz = xb[4096 + n];
        float f0 = cx - xb[m], f1 = cy - xb[2048 + m], f2 = cz - xb[4096 + m];
#pragma unroll
        for (int o = 0; o < 32; o++) {
            float h = bs1[o] + wl[o][0] * f0 + wl[o][1] * f1 + wl[o][2] * f2
                             + wl[o][3] * cx + wl[o][4] * cy + wl[o][5] * cz;
            h = h * sc[o] + sh[o];
            hn[t][o] = (h >= 0.f) ? h : 0.2f * h;
        }
    }
    __syncthreads();
    int o2 = t & 63, ng = t >> 6;
    float w2r[32];
#pragma unroll
    for (int c = 0; c < 32; c++) w2r[c] = w2[o2 * 32 + c];
    float bb = b2[o2];
#pragma unroll
    for (int ns = 0; ns < 4; ns++) {
        int nl = ng * 4 + ns;
        float mx = -1e30f;
#pragma unroll
        for (int kk = 0; kk < 16; kk++) {
            const float* hp = &hn[(nl << 4) + kk][0];
            float s = 0.f;
#pragma unroll
            for (int c4 = 0; c4 < 8; c4++) {
                float4 f = *(const float4*)(hp + c4 * 4);
                s += w2r[c4 * 4] * f.x + w2r[c4 * 4 + 1] * f.y
                   + w2r[c4 * 4 + 2] * f.z + w2r[c4 * 4 + 3] * f.w;
            }
            mx = fmaxf(mx, s);
        }
        x1full[((size_t)(b << 11) + n0 + nl) * 64 + o2] = mx + bb;
    }
}

// ---------------------------------------------------------------------------
// Farthest point sampling — distances in fp64 (exact for fp32 inputs).
// ---------------------------------------------------------------------------
__global__ __launch_bounds__(64) void fps_kernel(const float* __restrict__ x,
                                                 int* __restrict__ fpsidx)
{
    int b = blockIdx.x, l = threadIdx.x;
    const float* xb = x + (size_t)b * 3 * 2048;
    __shared__ float sx[2048], sy[2048], sz[2048];
    float px[32], py[32], pz[32];
    double dd[32];
#pragma unroll
    for (int j = 0; j < 32; j++) {
        int n = j * 64 + l;
        float a = xb[n], bb2 = xb[2048 + n], c = xb[4096 + n];
        px[j] = a; py[j] = bb2; pz[j] = c; dd[j] = 1e30;
        sx[n] = a; sy[n] = bb2; sz[n] = c;
    }
    __syncthreads();
    if (l == 0) fpsidx[(size_t)b * 512] = 0;
    int last = 0;
    for (int i = 1; i < 512; i++) {
        double lpx = (double)sx[last], lpy = (double)sy[last], lpz = (double)sz[last];
        double bestd = -1.0; int bestn = 0;
#pragma unroll
        for (int j = 0; j < 32; j++) {
            double dx = (double)px[j] - lpx, dy = (double)py[j] - lpy, dz = (double)pz[j] - lpz;
            double d = dx * dx + dy * dy + dz * dz;
            double nd = fmin(dd[j], d);
            dd[j] = nd;
            if (nd > bestd) { bestd = nd; bestn = j * 64 + l; }
        }
#pragma unroll
        for (int s = 1; s < 64; s <<= 1) {
            double od = __shfl_xor(bestd, s);
            int    on = __shfl_xor(bestn, s);
            if (od > bestd || (od == bestd && on < bestn)) { bestd = od; bestn = on; }
        }
        last = bestn;
        if (l == 0) fpsidx[(size_t)b * 512 + i] = bestn;
    }
}

// ---------------------------------------------------------------------------
// Gather x1 at fps indices into d_out channels [0,64).
// ---------------------------------------------------------------------------
__global__ __launch_bounds__(256) void gather_kernel(const float* __restrict__ x1full,
                                                     const int* __restrict__ fpsidx,
                                                     float* __restrict__ out)
{
    int e = blockIdx.x * 256 + threadIdx.x;   // < 32*64*512
    int j = e & 511; int rest = e >> 9; int c = rest & 63; int b = rest >> 6;
    int fj = fpsidx[b * 512 + j];
    out[((size_t)b * 832 + c) * 512 + j] = x1full[((size_t)(b << 11) + fj) * 64 + c];
}

// ---------------------------------------------------------------------------
// Squared norms per point (fp64) for a (B, C, 512) channel-major array.
// ---------------------------------------------------------------------------
template <int C>
__global__ __launch_bounds__(256) void norms_kernel(const float* __restrict__ xin,
                                                    size_t xbstride,
                                                    double* __restrict__ norms)
{
    int b = blockIdx.x >> 1;
    int n = ((blockIdx.x & 1) << 8) + threadIdx.x;
    const float* xb = xin + (size_t)b * xbstride;
    double s = 0.0;
    for (int c = 0; c < C; c++) { double v = (double)xb[(size_t)c * 512 + n]; s += v * v; }
    norms[(b << 9) + n] = s;
}

// ---------------------------------------------------------------------------
// Feature kNN (N=512), query x slice decomposition.
// Block = 256 thr = 16 queries x 16 slices (32 candidates each).
// Grid = 32 b * 32 qblocks = 1024.  fp64 accumulation, channel-ascending
// (bitwise identical values to the round-3 passing kernel).
// ---------------------------------------------------------------------------
template <int C, int KK>
__global__ __launch_bounds__(256) void knn_feat2_kernel(const float* __restrict__ xin,
                                                        size_t xbstride,
                                                        const double* __restrict__ norms,
                                                        int* __restrict__ idxout)
{
    constexpr int NN = 512, QB = 16, NS = 16, MS = NN / NS /*32*/, CC = 16;
    constexpr int CHUNKS = C / CC;
    __shared__ __align__(16) double smem[4736];
    float*  sm = (float*)smem;             // [CC][NN] chunk       (4096 dbl)
    float*  sq = (float*)(smem + 4096);    // [CC][QB]             (128 dbl)
    double* sn = smem + 4224;              // [NN]                 (512 dbl)
    double* mv = smem;                     // [QB][NS][KK]  overlay (<=2048 dbl)
    int*    mi = (int*)(smem + (size_t)QB * NS * KK);   // after mv

    int t = threadIdx.x;
    int q = t & 15, s = t >> 4;
    int b  = blockIdx.x >> 5;
    int n0 = (blockIdx.x & 31) << 4;
    int n  = n0 + q;
    const float* xb = xin + (size_t)b * xbstride;

    for (int e = t; e < NN; e += 256) sn[e] = norms[(b << 9) + e];

    double acc[MS];
#pragma unroll
    for (int i = 0; i < MS; ++i) acc[i] = 0.0;

    for (int ch = 0; ch < CHUNKS; ++ch) {
        int c0 = ch * CC;
        __syncthreads();
        for (int e = t; e < CC * NN; e += 256) {
            int c = e >> 9, m = e & 511;
            sm[c * NN + m] = xb[(size_t)(c0 + c) * NN + m];
        }
        {
            int c = t >> 4, qq = t & 15;
            sq[c * QB + qq] = xb[(size_t)(c0 + c) * NN + n0 + qq];
        }
        __syncthreads();
        double qv[CC];
#pragma unroll
        for (int cc = 0; cc < CC; ++cc) qv[cc] = (double)sq[cc * QB + q];
#pragma unroll
        for (int m4 = 0; m4 < MS / 4; ++m4) {
#pragma unroll
            for (int cc = 0; cc < CC; ++cc) {
                float4 f = *(const float4*)&sm[cc * NN + s * MS + m4 * 4];
                acc[m4 * 4 + 0] += qv[cc] * (double)f.x;
                acc[m4 * 4 + 1] += qv[cc] * (double)f.y;
                acc[m4 * 4 + 2] += qv[cc] * (double)f.z;
                acc[m4 * 4 + 3] += qv[cc] * (double)f.w;
            }
        }
    }

    double nq = sn[n];
    double bv[KK]; int bi[KK];
#pragma unroll
    for (int j = 0; j < KK; ++j) { bv[j] = -1e300; bi[j] = 0; }
#pragma unroll
    for (int mm = 0; mm < MS; ++mm) {
        int m = s * MS + mm;
        double val = 2.0 * acc[mm] - nq - sn[m];
        if (val > bv[KK - 1]) {
            bv[KK - 1] = val; bi[KK - 1] = m;
#pragma unroll
            for (int j = KK - 1; j > 0; --j) {
                if (bv[j] > bv[j - 1]) {
                    double tv = bv[j]; bv[j] = bv[j - 1]; bv[j - 1] = tv;
                    int    ti = bi[j]; bi[j] = bi[j - 1]; bi[j - 1] = ti;
                }
            }
        }
    }
    __syncthreads();   // sm reads done; overlay merge buffers
#pragma unroll
    for (int j = 0; j < KK; ++j) {
        mv[(q * NS + s) * KK + j] = bv[j];
        mi[(q * NS + s) * KK + j] = bi[j];
    }
    __syncthreads();
    if (t < QB) {
        int qq2 = t;
        double hv[NS]; int hj[NS];
#pragma unroll
        for (int s2 = 0; s2 < NS; ++s2) { hv[s2] = mv[(qq2 * NS + s2) * KK]; hj[s2] = 0; }
        int* op = idxout + ((size_t)(b * NN) + n0 + qq2) * KK;
#pragma unroll
        for (int r = 0; r < KK; ++r) {
            double best = -1e301; int bs = 0;
#pragma unroll
            for (int s2 = 0; s2 < NS; ++s2) {
                if (hv[s2] > best) { best = hv[s2]; bs = s2; }
            }
#pragma unroll
            for (int s2 = 0; s2 < NS; ++s2) {
                if (s2 == bs) {
                    op[r] = mi[(qq2 * NS + s2) * KK + hj[s2]];
                    hj[s2]++;
                    hv[s2] = (hj[s2] < KK) ? mv[(qq2 * NS + s2) * KK + hj[s2]] : -1e301;
                }
            }
        }
    }
}

// ---------------------------------------------------------------------------
// Generic edge-conv kernel for layers 2/3.
// ---------------------------------------------------------------------------
template <int C, int CO2, int KK, bool STATS>
__global__ __launch_bounds__(CO2) void edge_kernel(
    const float* __restrict__ xin, size_t xbstride, const int* __restrict__ idx,
    const float* __restrict__ w1, const float* __restrict__ b1,
    double* __restrict__ stats,
    const float* __restrict__ scsh, const float* __restrict__ w2,
    const float* __restrict__ b2,
    float* __restrict__ outp, size_t obstride, int tiles_per_block)
{
    constexpr int NN = 512, C2 = 2 * C, CCH = 16, TP = 32, TN = TP / KK;
    constexpr int CHUNKS = C2 / CCH;
    __shared__ float featc[TP][CCH + 4];
    __shared__ float wtl[CCH][CO2 + 1];
    __shared__ float hn[STATS ? 1 : TP * CO2];
    __shared__ int   smidx[TP];
    int t = threadIdx.x;
    float ssum = 0.f, ssq = 0.f;
    float bb1 = b1[t];

    for (int ti = 0; ti < tiles_per_block; ++ti) {
        int tileIdx = blockIdx.x * tiles_per_block + ti;
        int b = tileIdx / (NN / TN), nt = tileIdx % (NN / TN);
        int n0 = nt * TN;
        const float* xb = xin + (size_t)b * xbstride;
        if (t < TP) {
            int p = t, n = n0 + p / KK, kk = p % KK;
            smidx[p] = idx[((size_t)(b * NN) + n) * KK + kk];
        }
        float h[TP];
#pragma unroll
        for (int p = 0; p < TP; p++) h[p] = bb1;

        for (int ch = 0; ch < CHUNKS; ++ch) {
            int c0 = ch * CCH;
            __syncthreads();
            for (int e = t; e < TP * CCH; e += CO2) {
                int p = e & (TP - 1), ci = e >> 5;
                int c = c0 + ci;
                int n = n0 + p / KK;
                int m = smidx[p];
                float v = (c < C) ? (xb[(size_t)c * NN + n] - xb[(size_t)c * NN + m])
                                  : xb[(size_t)(c - C) * NN + n];
                featc[p][ci] = v;
            }
            for (int e = t; e < CCH * CO2; e += CO2) {
                int o = e / CCH, ci = e % CCH;
                wtl[ci][o] = w1[(size_t)o * C2 + c0 + ci];
            }
            __syncthreads();
#pragma unroll
            for (int c4 = 0; c4 < CCH / 4; c4++) {
                float a0 = wtl[c4 * 4][t], a1 = wtl[c4 * 4 + 1][t];
                float a2 = wtl[c4 * 4 + 2][t], a3 = wtl[c4 * 4 + 3][t];
#pragma unroll
                for (int p = 0; p < TP; p++) {
                    float4 f = *(const float4*)&featc[p][c4 * 4];
                    h[p] += a0 * f.x + a1 * f.y + a2 * f.z + a3 * f.w;
                }
            }
        }
        if constexpr (STATS) {
#pragma unroll
            for (int p = 0; p < TP; p++) { ssum += h[p]; ssq += h[p] * h[p]; }
        } else {
            float scv = scsh[t], shv = scsh[CO2 + t];
#pragma unroll
            for (int p = 0; p < TP; p++) {
                float v = h[p] * scv + shv;
                hn[p * CO2 + t] = (v >= 0.f) ? v : 0.2f * v;
            }
            for (int g = 0; g < 2; ++g) {
                float s[TP];
#pragma unroll
                for (int p = 0; p < TP; p++) s[p] = 0.f;
                for (int ch = 0; ch < CO2 / CCH; ++ch) {
                    int c0 = ch * CCH;
                    __syncthreads();
                    for (int e = t; e < CCH * CO2; e += CO2) {
                        int o = e / CCH, ci = e % CCH;
                        wtl[ci][o] = w2[((size_t)(g * CO2 + o)) * CO2 + c0 + ci];
                    }
                    __syncthreads();
#pragma unroll
                    for (int c4 = 0; c4 < CCH / 4; c4++) {
                        float a0 = wtl[c4 * 4][t], a1 = wtl[c4 * 4 + 1][t];
                        float a2 = wtl[c4 * 4 + 2][t], a3 = wtl[c4 * 4 + 3][t];
#pragma unroll
                        for (int p = 0; p < TP; p++) {
                            const float4 f = *(const float4*)&hn[p * CO2 + c0 + c4 * 4];
                            s[p] += a0 * f.x + a1 * f.y + a2 * f.z + a3 * f.w;
                        }
                    }
                }
                float bb2 = b2[g * CO2 + t];
#pragma unroll
                for (int nl = 0; nl < TN; ++nl) {
                    float mx = s[nl * KK];
#pragma unroll
                    for (int kk = 1; kk < KK; ++kk) mx = fmaxf(mx, s[nl * KK + kk]);
                    outp[(size_t)b * obstride + (size_t)(g * CO2 + t) * NN + n0 + nl] = mx + bb2;
                }
            }
        }
    }
    if constexpr (STATS) {
        atomicAdd(&stats[t], (double)ssum);
        atomicAdd(&stats[CO2 + t], (double)ssq);
    }
}

// ---------------------------------------------------------------------------
extern "C" void kernel_launch(void* const* d_in, const int* in_sizes, int n_in,
                              void* d_out, int out_size, void* d_ws, size_t ws_size,
                              hipStream_t stream)
{
    const float* x   = (const float*)d_in[0];
    const float* w1a = (const float*)d_in[1];
    const float* b1a = (const float*)d_in[2];
    const float* g1  = (const float*)d_in[3];
    const float* be1 = (const float*)d_in[4];
    const float* w1b = (const float*)d_in[5];
    const float* b1b = (const float*)d_in[6];
    const float* w2a = (const float*)d_in[7];
    const float* b2a = (const float*)d_in[8];
    const float* g2  = (const float*)d_in[9];
    const float* be2 = (const float*)d_in[10];
    const float* w2b = (const float*)d_in[11];
    const float* b2b = (const float*)d_in[12];
    const float* w3a = (const float*)d_in[13];
    const float* b3a = (const float*)d_in[14];
    const float* g3  = (const float*)d_in[15];
    const float* be3 = (const float*)d_in[16];
    const float* w3b = (const float*)d_in[17];
    const float* b3b = (const float*)d_in[18];

    float* out = (float*)d_out;
    float* fws = (float*)d_ws;
    int*    idx1   = (int*)(fws + OFF_IDX1);
    int*    idx2   = (int*)(fws + OFF_IDX2);
    int*    idx3   = (int*)(fws + OFF_IDX3);
    int*    fpsidx = (int*)(fws + OFF_FPS);
    double* st1 = (double*)(fws + OFF_ST);          // 64 doubles
    double* st2 = st1 + 64;                         // 256 doubles
    double* st3 = st2 + 256;                        // 512 doubles
    float*  ss1 = fws + OFF_SS1;
    float*  ss2 = fws + OFF_SS2;
    float*  ss3 = fws + OFF_SS3;
    double* nrm = (double*)(fws + OFF_NORM);
    float*  x1full = fws + OFF_X1F;

    const size_t OB = 832 * 512;   // per-batch stride of d_out

    // zero BN stat accumulators (832 doubles, contiguous)
    hipMemsetAsync(st1, 0, 832 * sizeof(double), stream);

    // ---- layer 1 ----
    knn3d2_kernel<<<4096, 256, 0, stream>>>(x, idx1);
    stats1_kernel<<<256, 256, 0, stream>>>(x, idx1, w1a, b1a, st1);
    finalize_kernel<<<1, 256, 0, stream>>>(st1, g1, be1, ss1, 32, 1.0 / 1048576.0);
    passB1_kernel<<<4096, 256, 0, stream>>>(x, idx1, w1a, b1a, ss1, w1b, b1b, x1full);

    // ---- fps + gather ----
    fps_kernel<<<32, 64, 0, stream>>>(x, fpsidx);
    gather_kernel<<<4096, 256, 0, stream>>>(x1full, fpsidx, out);

    // ---- layer 2 (input = out channels [0,64)) ----
    norms_kernel<64><<<64, 256, 0, stream>>>(out, OB, nrm);
    knn_feat2_kernel<64, 8><<<1024, 256, 0, stream>>>(out, OB, nrm, idx2);
    edge_kernel<64, 128, 8, true><<<512, 128, 0, stream>>>(
        out, OB, idx2, w2a, b2a, st2, nullptr, nullptr, nullptr, nullptr, 0, 8);
    finalize_kernel<<<1, 256, 0, stream>>>(st2, g2, be2, ss2, 128, 1.0 / 131072.0);
    edge_kernel<64, 128, 8, false><<<4096, 128, 0, stream>>>(
        out, OB, idx2, w2a, b2a, nullptr, ss2, w2b, b2b, out + 64 * 512, OB, 1);

    // ---- layer 3 (input = out channels [64,320)) ----
    norms_kernel<256><<<64, 256, 0, stream>>>(out + 64 * 512, OB, nrm);
    knn_feat2_kernel<256, 4><<<1024, 256, 0, stream>>>(out + 64 * 512, OB, nrm, idx3);
    edge_kernel<256, 256, 4, true><<<512, 256, 0, stream>>>(
        out + 64 * 512, OB, idx3, w3a, b3a, st3, nullptr, nullptr, nullptr, nullptr, 0, 4);
    finalize_kernel<<<1, 256, 0, stream>>>(st3, g3, be3, ss3, 256, 1.0 / 65536.0);
    edge_kernel<256, 256, 4, false><<<2048, 256, 0, stream>>>(
        out + 64 * 512, OB, idx3, w3a, b3a, nullptr, ss3, w3b, b3b, out + 320 * 512, OB, 1);
}

// Round 5
// 4165.345 us; speedup vs baseline: 1.4799x; 1.3110x over previous
//
#include <hip/hip_runtime.h>
#include <cstddef>

// ---------------------------------------------------------------------------
// Problem constants
//   x: (32, 3, 2048) fp32
//   layer1: C=3,  CO2=32,  CO=64,  K=16, N=2048
//   fps -> 512 points; gather x1
//   layer2: C=64, CO2=128, CO=256, K=8,  N=512
//   layer3: C=256,CO2=256, CO=512, K=4,  N=512
//   out: (32, 64+256+512=832, 512) fp32
//
// All discrete selections (knn top-k, fps argmax) computed in fp64 -> true
// ordering; downstream mean/max over k are order-invariant so per-query
// neighbor SET equality is sufficient.
// ---------------------------------------------------------------------------

// ---------------- workspace layout (in float units) ----------------
constexpr size_t OFF_IDX1 = 0;                         // int[32*2048*16]
constexpr size_t OFF_IDX2 = OFF_IDX1 + 1048576;        // int[32*512*8]
constexpr size_t OFF_IDX3 = OFF_IDX2 + 131072;         // int[32*512*4]
constexpr size_t OFF_FPS  = OFF_IDX3 + 65536;          // int[32*512]
constexpr size_t OFF_ST   = OFF_FPS + 16384;           // double[832] = 1664 floats
constexpr size_t OFF_SS1  = OFF_ST + 1664;             // float[64]
constexpr size_t OFF_SS2  = OFF_SS1 + 64;              // float[256]
constexpr size_t OFF_SS3  = OFF_SS2 + 256;             // float[512]
constexpr size_t OFF_NORM = OFF_SS3 + 512;             // double[32*512] = 32768 floats
constexpr size_t OFF_X1F  = OFF_NORM + 32768;          // float[32*2048*64] (B,N,C layout)

// ---------------------------------------------------------------------------
// Layer-1 kNN (C=3, N=2048, K=16).
// Block = 256 thr = 64 queries x 4 slices (512 candidates each).
// Grid = 32 b * 32 qblocks = 1024.  LDS = 40 KB (coords fp32 + norms fp64,
// merge buffers overlaid).  Scan staggered by s*8 -> conflict-free banks.
// ---------------------------------------------------------------------------
__global__ __launch_bounds__(256) void knn3d3_kernel(const float* __restrict__ x,
                                                     int* __restrict__ idx)
{
    constexpr int N = 2048, QB = 64, NS = 4, MS = N / NS /*512*/, KK = 16;
    __shared__ __align__(16) double smem[5120];        // 40960 B
    float*  sx  = (float*)smem;                        // [2048]
    float*  sy  = sx + 2048;                           // [2048]
    float*  sz  = sy + 2048;                           // [2048]  (3072 dbl)
    double* snd = smem + 3072;                         // [2048]  (-> 5120 dbl)
    double* mv  = smem;                                // overlay [QB][NS][KK] = 4096 dbl
    unsigned short* mi = (unsigned short*)(smem + 4096); // overlay 2048 u16 = 512 dbl

    int t = threadIdx.x;
    int q = t >> 2, s = t & 3;
    int b  = blockIdx.x >> 5;
    int n0 = (blockIdx.x & 31) << 6;
    int n  = n0 + q;
    const float* xb = x + (size_t)b * 3 * N;

    for (int e = t; e < N; e += 256) {
        float mx = xb[e], my = xb[N + e], mz = xb[2 * N + e];
        sx[e] = mx; sy[e] = my; sz[e] = mz;
        double dx = (double)mx, dy = (double)my, dz = (double)mz;
        snd[e] = dx * dx + dy * dy + dz * dz;
    }
    __syncthreads();

    double qx = (double)sx[n], qy = (double)sy[n], qz = (double)sz[n];
    double qq = snd[n];
    double bv[KK]; int bi[KK];
#pragma unroll
    for (int j = 0; j < KK; ++j) { bv[j] = -1e300; bi[j] = 0; }

#pragma unroll 4
    for (int i = 0; i < MS; ++i) {
        int mm = (i + s * 8) & (MS - 1);      // stagger -> conflict-free banks
        int m  = s * MS + mm;
        double dot = qx * (double)sx[m] + qy * (double)sy[m] + qz * (double)sz[m];
        double val = 2.0 * dot - qq - snd[m];
        if (val > bv[KK - 1]) {
            bv[KK - 1] = val; bi[KK - 1] = m;
#pragma unroll
            for (int j = KK - 1; j > 0; --j) {
                if (bv[j] > bv[j - 1]) {
                    double tv = bv[j]; bv[j] = bv[j - 1]; bv[j - 1] = tv;
                    int    ti = bi[j]; bi[j] = bi[j - 1]; bi[j - 1] = ti;
                }
            }
        }
    }
    __syncthreads();   // coord/norm reads done; overlay merge buffers
#pragma unroll
    for (int j = 0; j < KK; ++j) {
        mv[(q * NS + s) * KK + j] = bv[j];
        mi[(q * NS + s) * KK + j] = (unsigned short)bi[j];
    }
    __syncthreads();
    if (t < QB) {
        int qq2 = t;
        double hv[NS]; int hj[NS];
#pragma unroll
        for (int s2 = 0; s2 < NS; ++s2) { hv[s2] = mv[(qq2 * NS + s2) * KK]; hj[s2] = 0; }
        int* op = idx + ((size_t)(b * N) + n0 + qq2) * KK;
#pragma unroll
        for (int r = 0; r < KK; ++r) {
            double best = -1e301; int bs = 0;
#pragma unroll
            for (int s2 = 0; s2 < NS; ++s2) {
                if (hv[s2] > best) { best = hv[s2]; bs = s2; }
            }
#pragma unroll
            for (int s2 = 0; s2 < NS; ++s2) {
                if (s2 == bs) {
                    op[r] = (int)mi[(qq2 * NS + s2) * KK + hj[s2]];
                    hj[s2]++;
                    hv[s2] = (hj[s2] < KK) ? mv[(qq2 * NS + s2) * KK + hj[s2]] : -1e301;
                }
            }
        }
    }
}

// ---------------------------------------------------------------------------
// Layer-1 BN statistics
// ---------------------------------------------------------------------------
__global__ __launch_bounds__(256) void stats1_kernel(const float* __restrict__ x,
                                                     const int* __restrict__ idx1,
                                                     const float* __restrict__ w1,
                                                     const float* __restrict__ b1,
                                                     double* __restrict__ stats)
{
    __shared__ float wl[32][9];
    __shared__ float bsh[32];
    __shared__ float red[2][4][32];
    int t = threadIdx.x;
    for (int e = t; e < 192; e += 256) wl[e / 6][e % 6] = w1[e];
    if (t < 32) bsh[t] = b1[t];
    __syncthreads();

    float sum[32], sq[32];
#pragma unroll
    for (int o = 0; o < 32; o++) { sum[o] = 0.f; sq[o] = 0.f; }

    int base = blockIdx.x * 256 + t;
    for (int it = 0; it < 16; ++it) {
        int p = base + it * 65536;          // p < 2^20
        int b = p >> 15, rem = p & 32767, n = rem >> 4;
        int m = idx1[p];
        const float* xb = x + (size_t)b * 3 * 2048;
        float cx = xb[n], cy = xb[2048 + n], cz = xb[4096 + n];
        float f0 = cx - xb[m], f1 = cy - xb[2048 + m], f2 = cz - xb[4096 + m];
#pragma unroll
        for (int o = 0; o < 32; o++) {
            float h = bsh[o] + wl[o][0] * f0 + wl[o][1] * f1 + wl[o][2] * f2
                             + wl[o][3] * cx + wl[o][4] * cy + wl[o][5] * cz;
            sum[o] += h; sq[o] += h * h;
        }
    }
    int lane = t & 63, wv = t >> 6;
#pragma unroll
    for (int o = 0; o < 32; o++) {
        float s = sum[o], q = sq[o];
#pragma unroll
        for (int d = 1; d < 64; d <<= 1) { s += __shfl_xor(s, d); q += __shfl_xor(q, d); }
        if (lane == 0) { red[0][wv][o] = s; red[1][wv][o] = q; }
    }
    __syncthreads();
    if (t < 32) {
        atomicAdd(&stats[t], (double)(red[0][0][t] + red[0][1][t] + red[0][2][t] + red[0][3][t]));
    } else if (t < 64) {
        int o = t - 32;
        atomicAdd(&stats[32 + o], (double)(red[1][0][o] + red[1][1][o] + red[1][2][o] + red[1][3][o]));
    }
}

// ---------------------------------------------------------------------------
// scale/shift from (sum, sumsq) in fp64
// ---------------------------------------------------------------------------
__global__ void finalize_kernel(const double* __restrict__ stats,
                                const float* __restrict__ g,
                                const float* __restrict__ be,
                                float* __restrict__ scsh, int co2, double invcnt)
{
    int t = threadIdx.x;
    if (t < co2) {
        double mu  = stats[t] * invcnt;
        double var = stats[co2 + t] * invcnt - mu * mu;
        float  sc  = (float)((double)g[t] / sqrt(var + 1e-5));
        scsh[t]       = sc;
        scsh[co2 + t] = be[t] - (float)mu * sc;
    }
}

// ---------------------------------------------------------------------------
// Layer-1 pass B
// ---------------------------------------------------------------------------
__global__ __launch_bounds__(256) void passB1_kernel(const float* __restrict__ x,
                                                     const int* __restrict__ idx1,
                                                     const float* __restrict__ w1,
                                                     const float* __restrict__ b1,
                                                     const float* __restrict__ scsh,
                                                     const float* __restrict__ w2,
                                                     const float* __restrict__ b2,
                                                     float* __restrict__ x1full)
{
    __shared__ float hn[256][36];
    __shared__ float wl[32][9];
    __shared__ float sc[32], sh[32], bs1[32];
    int t = threadIdx.x;
    int b = blockIdx.x >> 7, nt = blockIdx.x & 127;
    int n0 = nt << 4;
    for (int e = t; e < 192; e += 256) wl[e / 6][e % 6] = w1[e];
    if (t < 32) { sc[t] = scsh[t]; sh[t] = scsh[32 + t]; bs1[t] = b1[t]; }
    __syncthreads();
    {
        int n = n0 + (t >> 4), kk = t & 15;
        int pix = (((b << 11) + n) << 4) + kk;
        int m = idx1[pix];
        const float* xb = x + (size_t)b * 3 * 2048;
        float cx = xb[n], cy = xb[2048 + n], cz = xb[4096 + n];
        float f0 = cx - xb[m], f1 = cy - xb[2048 + m], f2 = cz - xb[4096 + m];
#pragma unroll
        for (int o = 0; o < 32; o++) {
            float h = bs1[o] + wl[o][0] * f0 + wl[o][1] * f1 + wl[o][2] * f2
                             + wl[o][3] * cx + wl[o][4] * cy + wl[o][5] * cz;
            h = h * sc[o] + sh[o];
            hn[t][o] = (h >= 0.f) ? h : 0.2f * h;
        }
    }
    __syncthreads();
    int o2 = t & 63, ng = t >> 6;
    float w2r[32];
#pragma unroll
    for (int c = 0; c < 32; c++) w2r[c] = w2[o2 * 32 + c];
    float bb = b2[o2];
#pragma unroll
    for (int ns = 0; ns < 4; ns++) {
        int nl = ng * 4 + ns;
        float mx = -1e30f;
#pragma unroll
        for (int kk = 0; kk < 16; kk++) {
            const float* hp = &hn[(nl << 4) + kk][0];
            float s = 0.f;
#pragma unroll
            for (int c4 = 0; c4 < 8; c4++) {
                float4 f = *(const float4*)(hp + c4 * 4);
                s += w2r[c4 * 4] * f.x + w2r[c4 * 4 + 1] * f.y
                   + w2r[c4 * 4 + 2] * f.z + w2r[c4 * 4 + 3] * f.w;
            }
            mx = fmaxf(mx, s);
        }
        x1full[((size_t)(b << 11) + n0 + nl) * 64 + o2] = mx + bb;
    }
}

// ---------------------------------------------------------------------------
// Farthest point sampling — distances in fp64 (exact for fp32 inputs).
// ---------------------------------------------------------------------------
__global__ __launch_bounds__(64) void fps_kernel(const float* __restrict__ x,
                                                 int* __restrict__ fpsidx)
{
    int b = blockIdx.x, l = threadIdx.x;
    const float* xb = x + (size_t)b * 3 * 2048;
    __shared__ float sx[2048], sy[2048], sz[2048];
    float px[32], py[32], pz[32];
    double dd[32];
#pragma unroll
    for (int j = 0; j < 32; j++) {
        int n = j * 64 + l;
        float a = xb[n], bb2 = xb[2048 + n], c = xb[4096 + n];
        px[j] = a; py[j] = bb2; pz[j] = c; dd[j] = 1e30;
        sx[n] = a; sy[n] = bb2; sz[n] = c;
    }
    __syncthreads();
    if (l == 0) fpsidx[(size_t)b * 512] = 0;
    int last = 0;
    for (int i = 1; i < 512; i++) {
        double lpx = (double)sx[last], lpy = (double)sy[last], lpz = (double)sz[last];
        double bestd = -1.0; int bestn = 0;
#pragma unroll
        for (int j = 0; j < 32; j++) {
            double dx = (double)px[j] - lpx, dy = (double)py[j] - lpy, dz = (double)pz[j] - lpz;
            double d = dx * dx + dy * dy + dz * dz;
            double nd = fmin(dd[j], d);
            dd[j] = nd;
            if (nd > bestd) { bestd = nd; bestn = j * 64 + l; }
        }
#pragma unroll
        for (int s = 1; s < 64; s <<= 1) {
            double od = __shfl_xor(bestd, s);
            int    on = __shfl_xor(bestn, s);
            if (od > bestd || (od == bestd && on < bestn)) { bestd = od; bestn = on; }
        }
        last = bestn;
        if (l == 0) fpsidx[(size_t)b * 512 + i] = bestn;
    }
}

// ---------------------------------------------------------------------------
// Gather x1 at fps indices into d_out channels [0,64).
// ---------------------------------------------------------------------------
__global__ __launch_bounds__(256) void gather_kernel(const float* __restrict__ x1full,
                                                     const int* __restrict__ fpsidx,
                                                     float* __restrict__ out)
{
    int e = blockIdx.x * 256 + threadIdx.x;   // < 32*64*512
    int j = e & 511; int rest = e >> 9; int c = rest & 63; int b = rest >> 6;
    int fj = fpsidx[b * 512 + j];
    out[((size_t)b * 832 + c) * 512 + j] = x1full[((size_t)(b << 11) + fj) * 64 + c];
}

// ---------------------------------------------------------------------------
// Squared norms per point (fp64) for a (B, C, 512) channel-major array.
// ---------------------------------------------------------------------------
template <int C>
__global__ __launch_bounds__(256) void norms_kernel(const float* __restrict__ xin,
                                                    size_t xbstride,
                                                    double* __restrict__ norms)
{
    int b = blockIdx.x >> 1;
    int n = ((blockIdx.x & 1) << 8) + threadIdx.x;
    const float* xb = xin + (size_t)b * xbstride;
    double s = 0.0;
    for (int c = 0; c < C; c++) { double v = (double)xb[(size_t)c * 512 + n]; s += v * v; }
    norms[(b << 9) + n] = s;
}

// ---------------------------------------------------------------------------
// Feature kNN (N=512), query x slice decomposition.
// Block = 256 thr = 16 queries x 16 slices (32 candidates each).
// Grid = 32 b * 32 qblocks = 1024.
// ---------------------------------------------------------------------------
template <int C, int KK>
__global__ __launch_bounds__(256) void knn_feat2_kernel(const float* __restrict__ xin,
                                                        size_t xbstride,
                                                        const double* __restrict__ norms,
                                                        int* __restrict__ idxout)
{
    constexpr int NN = 512, QB = 16, NS = 16, MS = NN / NS /*32*/, CC = 16;
    constexpr int CHUNKS = C / CC;
    __shared__ __align__(16) double smem[4736];
    float*  sm = (float*)smem;             // [CC][NN] chunk       (4096 dbl)
    float*  sq = (float*)(smem + 4096);    // [CC][QB]             (128 dbl)
    double* sn = smem + 4224;              // [NN]                 (512 dbl)
    double* mv = smem;                     // [QB][NS][KK]  overlay (<=2048 dbl)
    int*    mi = (int*)(smem + (size_t)QB * NS * KK);   // after mv

    int t = threadIdx.x;
    int q = t & 15, s = t >> 4;
    int b  = blockIdx.x >> 5;
    int n0 = (blockIdx.x & 31) << 4;
    int n  = n0 + q;
    const float* xb = xin + (size_t)b * xbstride;

    for (int e = t; e < NN; e += 256) sn[e] = norms[(b << 9) + e];

    double acc[MS];
#pragma unroll
    for (int i = 0; i < MS; ++i) acc[i] = 0.0;

    for (int ch = 0; ch < CHUNKS; ++ch) {
        int c0 = ch * CC;
        __syncthreads();
        for (int e = t; e < CC * NN; e += 256) {
            int c = e >> 9, m = e & 511;
            sm[c * NN + m] = xb[(size_t)(c0 + c) * NN + m];
        }
        {
            int c = t >> 4, qq = t & 15;
            sq[c * QB + qq] = xb[(size_t)(c0 + c) * NN + n0 + qq];
        }
        __syncthreads();
        double qv[CC];
#pragma unroll
        for (int cc = 0; cc < CC; ++cc) qv[cc] = (double)sq[cc * QB + q];
#pragma unroll
        for (int m4 = 0; m4 < MS / 4; ++m4) {
#pragma unroll
            for (int cc = 0; cc < CC; ++cc) {
                float4 f = *(const float4*)&sm[cc * NN + s * MS + m4 * 4];
                acc[m4 * 4 + 0] += qv[cc] * (double)f.x;
                acc[m4 * 4 + 1] += qv[cc] * (double)f.y;
                acc[m4 * 4 + 2] += qv[cc] * (double)f.z;
                acc[m4 * 4 + 3] += qv[cc] * (double)f.w;
            }
        }
    }

    double nq = sn[n];
    double bv[KK]; int bi[KK];
#pragma unroll
    for (int j = 0; j < KK; ++j) { bv[j] = -1e300; bi[j] = 0; }
#pragma unroll
    for (int mm = 0; mm < MS; ++mm) {
        int m = s * MS + mm;
        double val = 2.0 * acc[mm] - nq - sn[m];
        if (val > bv[KK - 1]) {
            bv[KK - 1] = val; bi[KK - 1] = m;
#pragma unroll
            for (int j = KK - 1; j > 0; --j) {
                if (bv[j] > bv[j - 1]) {
                    double tv = bv[j]; bv[j] = bv[j - 1]; bv[j - 1] = tv;
                    int    ti = bi[j]; bi[j] = bi[j - 1]; bi[j - 1] = ti;
                }
            }
        }
    }
    __syncthreads();   // sm reads done; overlay merge buffers
#pragma unroll
    for (int j = 0; j < KK; ++j) {
        mv[(q * NS + s) * KK + j] = bv[j];
        mi[(q * NS + s) * KK + j] = bi[j];
    }
    __syncthreads();
    if (t < QB) {
        int qq2 = t;
        double hv[NS]; int hj[NS];
#pragma unroll
        for (int s2 = 0; s2 < NS; ++s2) { hv[s2] = mv[(qq2 * NS + s2) * KK]; hj[s2] = 0; }
        int* op = idxout + ((size_t)(b * NN) + n0 + qq2) * KK;
#pragma unroll
        for (int r = 0; r < KK; ++r) {
            double best = -1e301; int bs = 0;
#pragma unroll
            for (int s2 = 0; s2 < NS; ++s2) {
                if (hv[s2] > best) { best = hv[s2]; bs = s2; }
            }
#pragma unroll
            for (int s2 = 0; s2 < NS; ++s2) {
                if (s2 == bs) {
                    op[r] = mi[(qq2 * NS + s2) * KK + hj[s2]];
                    hj[s2]++;
                    hv[s2] = (hj[s2] < KK) ? mv[(qq2 * NS + s2) * KK + hj[s2]] : -1e301;
                }
            }
        }
    }
}

// ---------------------------------------------------------------------------
// Generic edge-conv kernel for layers 2/3.
// ---------------------------------------------------------------------------
template <int C, int CO2, int KK, bool STATS>
__global__ __launch_bounds__(CO2) void edge_kernel(
    const float* __restrict__ xin, size_t xbstride, const int* __restrict__ idx,
    const float* __restrict__ w1, const float* __restrict__ b1,
    double* __restrict__ stats,
    const float* __restrict__ scsh, const float* __restrict__ w2,
    const float* __restrict__ b2,
    float* __restrict__ outp, size_t obstride, int tiles_per_block)
{
    constexpr int NN = 512, C2 = 2 * C, CCH = 16, TP = 32, TN = TP / KK;
    constexpr int CHUNKS = C2 / CCH;
    __shared__ float featc[TP][CCH + 4];
    __shared__ float wtl[CCH][CO2 + 1];
    __shared__ float hn[STATS ? 1 : TP * CO2];
    __shared__ int   smidx[TP];
    int t = threadIdx.x;
    float ssum = 0.f, ssq = 0.f;
    float bb1 = b1[t];

    for (int ti = 0; ti < tiles_per_block; ++ti) {
        int tileIdx = blockIdx.x * tiles_per_block + ti;
        int b = tileIdx / (NN / TN), nt = tileIdx % (NN / TN);
        int n0 = nt * TN;
        const float* xb = xin + (size_t)b * xbstride;
        if (t < TP) {
            int p = t, n = n0 + p / KK, kk = p % KK;
            smidx[p] = idx[((size_t)(b * NN) + n) * KK + kk];
        }
        float h[TP];
#pragma unroll
        for (int p = 0; p < TP; p++) h[p] = bb1;

        for (int ch = 0; ch < CHUNKS; ++ch) {
            int c0 = ch * CCH;
            __syncthreads();
            for (int e = t; e < TP * CCH; e += CO2) {
                int p = e & (TP - 1), ci = e >> 5;
                int c = c0 + ci;
                int n = n0 + p / KK;
                int m = smidx[p];
                float v = (c < C) ? (xb[(size_t)c * NN + n] - xb[(size_t)c * NN + m])
                                  : xb[(size_t)(c - C) * NN + n];
                featc[p][ci] = v;
            }
            for (int e = t; e < CCH * CO2; e += CO2) {
                int o = e / CCH, ci = e % CCH;
                wtl[ci][o] = w1[(size_t)o * C2 + c0 + ci];
            }
            __syncthreads();
#pragma unroll
            for (int c4 = 0; c4 < CCH / 4; c4++) {
                float a0 = wtl[c4 * 4][t], a1 = wtl[c4 * 4 + 1][t];
                float a2 = wtl[c4 * 4 + 2][t], a3 = wtl[c4 * 4 + 3][t];
#pragma unroll
                for (int p = 0; p < TP; p++) {
                    float4 f = *(const float4*)&featc[p][c4 * 4];
                    h[p] += a0 * f.x + a1 * f.y + a2 * f.z + a3 * f.w;
                }
            }
        }
        if constexpr (STATS) {
#pragma unroll
            for (int p = 0; p < TP; p++) { ssum += h[p]; ssq += h[p] * h[p]; }
        } else {
            float scv = scsh[t], shv = scsh[CO2 + t];
#pragma unroll
            for (int p = 0; p < TP; p++) {
                float v = h[p] * scv + shv;
                hn[p * CO2 + t] = (v >= 0.f) ? v : 0.2f * v;
            }
            for (int g = 0; g < 2; ++g) {
                float s[TP];
#pragma unroll
                for (int p = 0; p < TP; p++) s[p] = 0.f;
                for (int ch = 0; ch < CO2 / CCH; ++ch) {
                    int c0 = ch * CCH;
                    __syncthreads();
                    for (int e = t; e < CCH * CO2; e += CO2) {
                        int o = e / CCH, ci = e % CCH;
                        wtl[ci][o] = w2[((size_t)(g * CO2 + o)) * CO2 + c0 + ci];
                    }
                    __syncthreads();
#pragma unroll
                    for (int c4 = 0; c4 < CCH / 4; c4++) {
                        float a0 = wtl[c4 * 4][t], a1 = wtl[c4 * 4 + 1][t];
                        float a2 = wtl[c4 * 4 + 2][t], a3 = wtl[c4 * 4 + 3][t];
#pragma unroll
                        for (int p = 0; p < TP; p++) {
                            const float4 f = *(const float4*)&hn[p * CO2 + c0 + c4 * 4];
                            s[p] += a0 * f.x + a1 * f.y + a2 * f.z + a3 * f.w;
                        }
                    }
                }
                float bb2 = b2[g * CO2 + t];
#pragma unroll
                for (int nl = 0; nl < TN; ++nl) {
                    float mx = s[nl * KK];
#pragma unroll
                    for (int kk = 1; kk < KK; ++kk) mx = fmaxf(mx, s[nl * KK + kk]);
                    outp[(size_t)b * obstride + (size_t)(g * CO2 + t) * NN + n0 + nl] = mx + bb2;
                }
            }
        }
    }
    if constexpr (STATS) {
        atomicAdd(&stats[t], (double)ssum);
        atomicAdd(&stats[CO2 + t], (double)ssq);
    }
}

// ---------------------------------------------------------------------------
extern "C" void kernel_launch(void* const* d_in, const int* in_sizes, int n_in,
                              void* d_out, int out_size, void* d_ws, size_t ws_size,
                              hipStream_t stream)
{
    const float* x   = (const float*)d_in[0];
    const float* w1a = (const float*)d_in[1];
    const float* b1a = (const float*)d_in[2];
    const float* g1  = (const float*)d_in[3];
    const float* be1 = (const float*)d_in[4];
    const float* w1b = (const float*)d_in[5];
    const float* b1b = (const float*)d_in[6];
    const float* w2a = (const float*)d_in[7];
    const float* b2a = (const float*)d_in[8];
    const float* g2  = (const float*)d_in[9];
    const float* be2 = (const float*)d_in[10];
    const float* w2b = (const float*)d_in[11];
    const float* b2b = (const float*)d_in[12];
    const float* w3a = (const float*)d_in[13];
    const float* b3a = (const float*)d_in[14];
    const float* g3  = (const float*)d_in[15];
    const float* be3 = (const float*)d_in[16];
    const float* w3b = (const float*)d_in[17];
    const float* b3b = (const float*)d_in[18];

    float* out = (float*)d_out;
    float* fws = (float*)d_ws;
    int*    idx1   = (int*)(fws + OFF_IDX1);
    int*    idx2   = (int*)(fws + OFF_IDX2);
    int*    idx3   = (int*)(fws + OFF_IDX3);
    int*    fpsidx = (int*)(fws + OFF_FPS);
    double* st1 = (double*)(fws + OFF_ST);          // 64 doubles
    double* st2 = st1 + 64;                         // 256 doubles
    double* st3 = st2 + 256;                        // 512 doubles
    float*  ss1 = fws + OFF_SS1;
    float*  ss2 = fws + OFF_SS2;
    float*  ss3 = fws + OFF_SS3;
    double* nrm = (double*)(fws + OFF_NORM);
    float*  x1full = fws + OFF_X1F;

    const size_t OB = 832 * 512;   // per-batch stride of d_out

    // zero BN stat accumulators (832 doubles, contiguous)
    hipMemsetAsync(st1, 0, 832 * sizeof(double), stream);

    // ---- layer 1 ----
    knn3d3_kernel<<<1024, 256, 0, stream>>>(x, idx1);
    stats1_kernel<<<256, 256, 0, stream>>>(x, idx1, w1a, b1a, st1);
    finalize_kernel<<<1, 256, 0, stream>>>(st1, g1, be1, ss1, 32, 1.0 / 1048576.0);
    passB1_kernel<<<4096, 256, 0, stream>>>(x, idx1, w1a, b1a, ss1, w1b, b1b, x1full);

    // ---- fps + gather ----
    fps_kernel<<<32, 64, 0, stream>>>(x, fpsidx);
    gather_kernel<<<4096, 256, 0, stream>>>(x1full, fpsidx, out);

    // ---- layer 2 (input = out channels [0,64)) ----
    norms_kernel<64><<<64, 256, 0, stream>>>(out, OB, nrm);
    knn_feat2_kernel<64, 8><<<1024, 256, 0, stream>>>(out, OB, nrm, idx2);
    edge_kernel<64, 128, 8, true><<<512, 128, 0, stream>>>(
        out, OB, idx2, w2a, b2a, st2, nullptr, nullptr, nullptr, nullptr, 0, 8);
    finalize_kernel<<<1, 256, 0, stream>>>(st2, g2, be2, ss2, 128, 1.0 / 131072.0);
    edge_kernel<64, 128, 8, false><<<4096, 128, 0, stream>>>(
        out, OB, idx2, w2a, b2a, nullptr, ss2, w2b, b2b, out + 64 * 512, OB, 1);

    // ---- layer 3 (input = out channels [64,320)) ----
    norms_kernel<256><<<64, 256, 0, stream>>>(out + 64 * 512, OB, nrm);
    knn_feat2_kernel<256, 4><<<1024, 256, 0, stream>>>(out + 64 * 512, OB, nrm, idx3);
    edge_kernel<256, 256, 4, true><<<512, 256, 0, stream>>>(
        out + 64 * 512, OB, idx3, w3a, b3a, st3, nullptr, nullptr, nullptr, nullptr, 0, 4);
    finalize_kernel<<<1, 256, 0, stream>>>(st3, g3, be3, ss3, 256, 1.0 / 65536.0);
    edge_kernel<256, 256, 4, false><<<2048, 256, 0, stream>>>(
        out + 64 * 512, OB, idx3, w3a, b3a, nullptr, ss3, w3b, b3b, out + 320 * 512, OB, 1);
}

// Round 7
// 2633.408 us; speedup vs baseline: 2.3409x; 1.5817x over previous
//
#include <hip/hip_runtime.h>
#include <hip/hip_bf16.h>
#include <cstddef>

// ---------------------------------------------------------------------------
// Problem constants
//   x: (32, 3, 2048) fp32
//   layer1: C=3,  CO2=32,  CO=64,  K=16, N=2048
//   fps -> 512 points; gather x1
//   layer2: C=64, CO2=128, CO=256, K=8,  N=512
//   layer3: C=256,CO2=256, CO=512, K=4,  N=512
//   out: (32, 64+256+512=832, 512) fp32
//
// Edge-conv first matmul via G/H decomposition:
//   h[:,n,k] = G[n] - H[m(n,k)],  G = (W_L+W_R)x + b1,  H = W_L x.
// L2 G/H kept fp32 (upstream of kNN-3 selection!); L3 G/H stored bf16
// (terminal layer, no selection downstream, max/BN are non-amplifying).
// All discrete selections (knn top-k, fps argmax) remain fp64-exact.
// ---------------------------------------------------------------------------

// ---------------- workspace layout (in float units) ----------------
constexpr size_t OFF_IDX1 = 0;                         // int[32*2048*16]
constexpr size_t OFF_IDX2 = OFF_IDX1 + 1048576;        // int[32*512*8]
constexpr size_t OFF_IDX3 = OFF_IDX2 + 131072;         // int[32*512*4]
constexpr size_t OFF_FPS  = OFF_IDX3 + 65536;          // int[32*512]
constexpr size_t OFF_ST   = OFF_FPS + 16384;           // double[832] = 1664 floats
constexpr size_t OFF_SS1  = OFF_ST + 1664;             // float[64]
constexpr size_t OFF_SS2  = OFF_SS1 + 64;              // float[256]
constexpr size_t OFF_SS3  = OFF_SS2 + 256;             // float[512]
constexpr size_t OFF_NORM = OFF_SS3 + 512;             // double[32*512] = 32768 floats
constexpr size_t OFF_X1F  = OFF_NORM + 32768;          // 4,194,304-float multi-use region:
// phase 1: x1full fp32 [32][2048][64]
// phase 2: G2,H2 fp32 [32][512][128] each (2*2,097,152)
// phase 3: G3,H3 bf16 [32][512][256] each (2*4,194,304 bf16 = 4,194,304 fl)

// ---------------------------------------------------------------------------
// Layer-1 kNN (C=3, N=2048, K=16).  64 queries x 4 slices per 256-thr block.
// ---------------------------------------------------------------------------
__global__ __launch_bounds__(256) void knn3d3_kernel(const float* __restrict__ x,
                                                     int* __restrict__ idx)
{
    constexpr int N = 2048, QB = 64, NS = 4, MS = N / NS /*512*/, KK = 16;
    __shared__ __align__(16) double smem[5120];        // 40960 B
    float*  sx  = (float*)smem;                        // [2048]
    float*  sy  = sx + 2048;                           // [2048]
    float*  sz  = sy + 2048;                           // [2048]  (3072 dbl)
    double* snd = smem + 3072;                         // [2048]  (-> 5120 dbl)
    double* mv  = smem;                                // overlay [QB][NS][KK] = 4096 dbl
    unsigned short* mi = (unsigned short*)(smem + 4096); // overlay 2048 u16

    int t = threadIdx.x;
    int q = t >> 2, s = t & 3;
    int b  = blockIdx.x >> 5;
    int n0 = (blockIdx.x & 31) << 6;
    int n  = n0 + q;
    const float* xb = x + (size_t)b * 3 * N;

    for (int e = t; e < N; e += 256) {
        float mx = xb[e], my = xb[N + e], mz = xb[2 * N + e];
        sx[e] = mx; sy[e] = my; sz[e] = mz;
        double dx = (double)mx, dy = (double)my, dz = (double)mz;
        snd[e] = dx * dx + dy * dy + dz * dz;
    }
    __syncthreads();

    double qx = (double)sx[n], qy = (double)sy[n], qz = (double)sz[n];
    double qq = snd[n];
    double bv[KK]; int bi[KK];
#pragma unroll
    for (int j = 0; j < KK; ++j) { bv[j] = -1e300; bi[j] = 0; }

#pragma unroll 4
    for (int i = 0; i < MS; ++i) {
        int mm = (i + s * 8) & (MS - 1);
        int m  = s * MS + mm;
        double dot = qx * (double)sx[m] + qy * (double)sy[m] + qz * (double)sz[m];
        double val = 2.0 * dot - qq - snd[m];
        if (val > bv[KK - 1]) {
            bv[KK - 1] = val; bi[KK - 1] = m;
#pragma unroll
            for (int j = KK - 1; j > 0; --j) {
                if (bv[j] > bv[j - 1]) {
                    double tv = bv[j]; bv[j] = bv[j - 1]; bv[j - 1] = tv;
                    int    ti = bi[j]; bi[j] = bi[j - 1]; bi[j - 1] = ti;
                }
            }
        }
    }
    __syncthreads();
#pragma unroll
    for (int j = 0; j < KK; ++j) {
        mv[(q * NS + s) * KK + j] = bv[j];
        mi[(q * NS + s) * KK + j] = (unsigned short)bi[j];
    }
    __syncthreads();
    if (t < QB) {
        int qq2 = t;
        double hv[NS]; int hj[NS];
#pragma unroll
        for (int s2 = 0; s2 < NS; ++s2) { hv[s2] = mv[(qq2 * NS + s2) * KK]; hj[s2] = 0; }
        int* op = idx + ((size_t)(b * N) + n0 + qq2) * KK;
#pragma unroll
        for (int r = 0; r < KK; ++r) {
            double best = -1e301; int bs = 0;
#pragma unroll
            for (int s2 = 0; s2 < NS; ++s2) {
                if (hv[s2] > best) { best = hv[s2]; bs = s2; }
            }
#pragma unroll
            for (int s2 = 0; s2 < NS; ++s2) {
                if (s2 == bs) {
                    op[r] = (int)mi[(qq2 * NS + s2) * KK + hj[s2]];
                    hj[s2]++;
                    hv[s2] = (hj[s2] < KK) ? mv[(qq2 * NS + s2) * KK + hj[s2]] : -1e301;
                }
            }
        }
    }
}

// ---------------------------------------------------------------------------
// Layer-1 BN statistics
// ---------------------------------------------------------------------------
__global__ __launch_bounds__(256) void stats1_kernel(const float* __restrict__ x,
                                                     const int* __restrict__ idx1,
                                                     const float* __restrict__ w1,
                                                     const float* __restrict__ b1,
                                                     double* __restrict__ stats)
{
    __shared__ float wl[32][9];
    __shared__ float bsh[32];
    __shared__ float red[2][4][32];
    int t = threadIdx.x;
    for (int e = t; e < 192; e += 256) wl[e / 6][e % 6] = w1[e];
    if (t < 32) bsh[t] = b1[t];
    __syncthreads();

    float sum[32], sq[32];
#pragma unroll
    for (int o = 0; o < 32; o++) { sum[o] = 0.f; sq[o] = 0.f; }

    int base = blockIdx.x * 256 + t;
    for (int it = 0; it < 16; ++it) {
        int p = base + it * 65536;
        int b = p >> 15, rem = p & 32767, n = rem >> 4;
        int m = idx1[p];
        const float* xb = x + (size_t)b * 3 * 2048;
        float cx = xb[n], cy = xb[2048 + n], cz = xb[4096 + n];
        float f0 = cx - xb[m], f1 = cy - xb[2048 + m], f2 = cz - xb[4096 + m];
#pragma unroll
        for (int o = 0; o < 32; o++) {
            float h = bsh[o] + wl[o][0] * f0 + wl[o][1] * f1 + wl[o][2] * f2
                             + wl[o][3] * cx + wl[o][4] * cy + wl[o][5] * cz;
            sum[o] += h; sq[o] += h * h;
        }
    }
    int lane = t & 63, wv = t >> 6;
#pragma unroll
    for (int o = 0; o < 32; o++) {
        float s = sum[o], q = sq[o];
#pragma unroll
        for (int d = 1; d < 64; d <<= 1) { s += __shfl_xor(s, d); q += __shfl_xor(q, d); }
        if (lane == 0) { red[0][wv][o] = s; red[1][wv][o] = q; }
    }
    __syncthreads();
    if (t < 32) {
        atomicAdd(&stats[t], (double)(red[0][0][t] + red[0][1][t] + red[0][2][t] + red[0][3][t]));
    } else if (t < 64) {
        int o = t - 32;
        atomicAdd(&stats[32 + o], (double)(red[1][0][o] + red[1][1][o] + red[1][2][o] + red[1][3][o]));
    }
}

// ---------------------------------------------------------------------------
// scale/shift from (sum, sumsq) in fp64
// ---------------------------------------------------------------------------
__global__ void finalize_kernel(const double* __restrict__ stats,
                                const float* __restrict__ g,
                                const float* __restrict__ be,
                                float* __restrict__ scsh, int co2, double invcnt)
{
    int t = threadIdx.x;
    if (t < co2) {
        double mu  = stats[t] * invcnt;
        double var = stats[co2 + t] * invcnt - mu * mu;
        float  sc  = (float)((double)g[t] / sqrt(var + 1e-5));
        scsh[t]       = sc;
        scsh[co2 + t] = be[t] - (float)mu * sc;
    }
}

// ---------------------------------------------------------------------------
// Layer-1 pass B
// ---------------------------------------------------------------------------
__global__ __launch_bounds__(256) void passB1_kernel(const float* __restrict__ x,
                                                     const int* __restrict__ idx1,
                                                     const float* __restrict__ w1,
                                                     const float* __restrict__ b1,
                                                     const float* __restrict__ scsh,
                                                     const float* __restrict__ w2,
                                                     const float* __restrict__ b2,
                                                     float* __restrict__ x1full)
{
    __shared__ float hn[256][36];
    __shared__ float wl[32][9];
    __shared__ float sc[32], sh[32], bs1[32];
    int t = threadIdx.x;
    int b = blockIdx.x >> 7, nt = blockIdx.x & 127;
    int n0 = nt << 4;
    for (int e = t; e < 192; e += 256) wl[e / 6][e % 6] = w1[e];
    if (t < 32) { sc[t] = scsh[t]; sh[t] = scsh[32 + t]; bs1[t] = b1[t]; }
    __syncthreads();
    {
        int n = n0 + (t >> 4), kk = t & 15;
        int pix = (((b << 11) + n) << 4) + kk;
        int m = idx1[pix];
        const float* xb = x + (size_t)b * 3 * 2048;
        float cx = xb[n], cy = xb[2048 + n], cz = xb[4096 + n];
        float f0 = cx - xb[m], f1 = cy - xb[2048 + m], f2 = cz - xb[4096 + m];
#pragma unroll
        for (int o = 0; o < 32; o++) {
            float h = bs1[o] + wl[o][0] * f0 + wl[o][1] * f1 + wl[o][2] * f2
                             + wl[o][3] * cx + wl[o][4] * cy + wl[o][5] * cz;
            h = h * sc[o] + sh[o];
            hn[t][o] = (h >= 0.f) ? h : 0.2f * h;
        }
    }
    __syncthreads();
    int o2 = t & 63, ng = t >> 6;
    float w2r[32];
#pragma unroll
    for (int c = 0; c < 32; c++) w2r[c] = w2[o2 * 32 + c];
    float bb = b2[o2];
#pragma unroll
    for (int ns = 0; ns < 4; ns++) {
        int nl = ng * 4 + ns;
        float mx = -1e30f;
#pragma unroll
        for (int kk = 0; kk < 16; kk++) {
            const float* hp = &hn[(nl << 4) + kk][0];
            float s = 0.f;
#pragma unroll
            for (int c4 = 0; c4 < 8; c4++) {
                float4 f = *(const float4*)(hp + c4 * 4);
                s += w2r[c4 * 4] * f.x + w2r[c4 * 4 + 1] * f.y
                   + w2r[c4 * 4 + 2] * f.z + w2r[c4 * 4 + 3] * f.w;
            }
            mx = fmaxf(mx, s);
        }
        x1full[((size_t)(b << 11) + n0 + nl) * 64 + o2] = mx + bb;
    }
}

// ---------------------------------------------------------------------------
// Farthest point sampling — fp64 distances.
// ---------------------------------------------------------------------------
__global__ __launch_bounds__(64) void fps_kernel(const float* __restrict__ x,
                                                 int* __restrict__ fpsidx)
{
    int b = blockIdx.x, l = threadIdx.x;
    const float* xb = x + (size_t)b * 3 * 2048;
    __shared__ float sx[2048], sy[2048], sz[2048];
    float px[32], py[32], pz[32];
    double dd[32];
#pragma unroll
    for (int j = 0; j < 32; j++) {
        int n = j * 64 + l;
        float a = xb[n], bb2 = xb[2048 + n], c = xb[4096 + n];
        px[j] = a; py[j] = bb2; pz[j] = c; dd[j] = 1e30;
        sx[n] = a; sy[n] = bb2; sz[n] = c;
    }
    __syncthreads();
    if (l == 0) fpsidx[(size_t)b * 512] = 0;
    int last = 0;
    for (int i = 1; i < 512; i++) {
        double lpx = (double)sx[last], lpy = (double)sy[last], lpz = (double)sz[last];
        double bestd = -1.0; int bestn = 0;
#pragma unroll
        for (int j = 0; j < 32; j++) {
            double dx = (double)px[j] - lpx, dy = (double)py[j] - lpy, dz = (double)pz[j] - lpz;
            double d = dx * dx + dy * dy + dz * dz;
            double nd = fmin(dd[j], d);
            dd[j] = nd;
            if (nd > bestd) { bestd = nd; bestn = j * 64 + l; }
        }
#pragma unroll
        for (int s = 1; s < 64; s <<= 1) {
            double od = __shfl_xor(bestd, s);
            int    on = __shfl_xor(bestn, s);
            if (od > bestd || (od == bestd && on < bestn)) { bestd = od; bestn = on; }
        }
        last = bestn;
        if (l == 0) fpsidx[(size_t)b * 512 + i] = bestn;
    }
}

// ---------------------------------------------------------------------------
// Gather x1 at fps indices into d_out channels [0,64).
// ---------------------------------------------------------------------------
__global__ __launch_bounds__(256) void gather_kernel(const float* __restrict__ x1full,
                                                     const int* __restrict__ fpsidx,
                                                     float* __restrict__ out)
{
    int e = blockIdx.x * 256 + threadIdx.x;
    int j = e & 511; int rest = e >> 9; int c = rest & 63; int b = rest >> 6;
    int fj = fpsidx[b * 512 + j];
    out[((size_t)b * 832 + c) * 512 + j] = x1full[((size_t)(b << 11) + fj) * 64 + c];
}

// ---------------------------------------------------------------------------
// Squared norms per point (fp64).
// ---------------------------------------------------------------------------
template <int C>
__global__ __launch_bounds__(256) void norms_kernel(const float* __restrict__ xin,
                                                    size_t xbstride,
                                                    double* __restrict__ norms)
{
    int b = blockIdx.x >> 1;
    int n = ((blockIdx.x & 1) << 8) + threadIdx.x;
    const float* xb = xin + (size_t)b * xbstride;
    double s = 0.0;
    for (int c = 0; c < C; c++) { double v = (double)xb[(size_t)c * 512 + n]; s += v * v; }
    norms[(b << 9) + n] = s;
}

// ---------------------------------------------------------------------------
// Feature kNN (N=512), 16 queries x 16 slices per block, fp64 exact.
// ---------------------------------------------------------------------------
template <int C, int KK>
__global__ __launch_bounds__(256) void knn_feat2_kernel(const float* __restrict__ xin,
                                                        size_t xbstride,
                                                        const double* __restrict__ norms,
                                                        int* __restrict__ idxout)
{
    constexpr int NN = 512, QB = 16, NS = 16, MS = NN / NS /*32*/, CC = 16;
    constexpr int CHUNKS = C / CC;
    __shared__ __align__(16) double smem[4736];
    float*  sm = (float*)smem;             // [CC][NN]
    float*  sq = (float*)(smem + 4096);    // [CC][QB]
    double* sn = smem + 4224;              // [NN]
    double* mv = smem;                     // overlay [QB][NS][KK]
    int*    mi = (int*)(smem + (size_t)QB * NS * KK);

    int t = threadIdx.x;
    int q = t & 15, s = t >> 4;
    int b  = blockIdx.x >> 5;
    int n0 = (blockIdx.x & 31) << 4;
    int n  = n0 + q;
    const float* xb = xin + (size_t)b * xbstride;

    for (int e = t; e < NN; e += 256) sn[e] = norms[(b << 9) + e];

    double acc[MS];
#pragma unroll
    for (int i = 0; i < MS; ++i) acc[i] = 0.0;

    for (int ch = 0; ch < CHUNKS; ++ch) {
        int c0 = ch * CC;
        __syncthreads();
        for (int e = t; e < CC * NN; e += 256) {
            int c = e >> 9, m = e & 511;
            sm[c * NN + m] = xb[(size_t)(c0 + c) * NN + m];
        }
        {
            int c = t >> 4, qq = t & 15;
            sq[c * QB + qq] = xb[(size_t)(c0 + c) * NN + n0 + qq];
        }
        __syncthreads();
        double qv[CC];
#pragma unroll
        for (int cc = 0; cc < CC; ++cc) qv[cc] = (double)sq[cc * QB + q];
#pragma unroll
        for (int m4 = 0; m4 < MS / 4; ++m4) {
#pragma unroll
            for (int cc = 0; cc < CC; ++cc) {
                float4 f = *(const float4*)&sm[cc * NN + s * MS + m4 * 4];
                acc[m4 * 4 + 0] += qv[cc] * (double)f.x;
                acc[m4 * 4 + 1] += qv[cc] * (double)f.y;
                acc[m4 * 4 + 2] += qv[cc] * (double)f.z;
                acc[m4 * 4 + 3] += qv[cc] * (double)f.w;
            }
        }
    }

    double nq = sn[n];
    double bv[KK]; int bi[KK];
#pragma unroll
    for (int j = 0; j < KK; ++j) { bv[j] = -1e300; bi[j] = 0; }
#pragma unroll
    for (int mm = 0; mm < MS; ++mm) {
        int m = s * MS + mm;
        double val = 2.0 * acc[mm] - nq - sn[m];
        if (val > bv[KK - 1]) {
            bv[KK - 1] = val; bi[KK - 1] = m;
#pragma unroll
            for (int j = KK - 1; j > 0; --j) {
                if (bv[j] > bv[j - 1]) {
                    double tv = bv[j]; bv[j] = bv[j - 1]; bv[j - 1] = tv;
                    int    ti = bi[j]; bi[j] = bi[j - 1]; bi[j - 1] = ti;
                }
            }
        }
    }
    __syncthreads();
#pragma unroll
    for (int j = 0; j < KK; ++j) {
        mv[(q * NS + s) * KK + j] = bv[j];
        mi[(q * NS + s) * KK + j] = bi[j];
    }
    __syncthreads();
    if (t < QB) {
        int qq2 = t;
        double hv[NS]; int hj[NS];
#pragma unroll
        for (int s2 = 0; s2 < NS; ++s2) { hv[s2] = mv[(qq2 * NS + s2) * KK]; hj[s2] = 0; }
        int* op = idxout + ((size_t)(b * NN) + n0 + qq2) * KK;
#pragma unroll
        for (int r = 0; r < KK; ++r) {
            double best = -1e301; int bs = 0;
#pragma unroll
            for (int s2 = 0; s2 < NS; ++s2) {
                if (hv[s2] > best) { best = hv[s2]; bs = s2; }
            }
#pragma unroll
            for (int s2 = 0; s2 < NS; ++s2) {
                if (s2 == bs) {
                    op[r] = mi[(qq2 * NS + s2) * KK + hj[s2]];
                    hj[s2]++;
                    hv[s2] = (hj[s2] < KK) ? mv[(qq2 * NS + s2) * KK + hj[s2]] : -1e301;
                }
            }
        }
    }
}

// ---------------------------------------------------------------------------
// G/H precompute GEMM:  G[b][n][o] = b1[o] + sum_c (wL+wR)[o][c] x[c][n]
//                       H[b][n][o] =         sum_c  wL[o][c]     x[c][n]
// Block 256 thr = 16 n-lanes x 16 o-lanes; each thread 8 n x 4 o x {G,H}.
// Tile: 128 n x 64 o.  Grid = 32b * (512/128) * (CO2/64).
// ---------------------------------------------------------------------------
template <int C, int CO2, bool BF16OUT>
__global__ __launch_bounds__(256) void gh_kernel(const float* __restrict__ xin,
                                                 size_t xbstride,
                                                 const float* __restrict__ w1,
                                                 const float* __restrict__ b1,
                                                 void* __restrict__ Gout,
                                                 void* __restrict__ Hout)
{
    constexpr int TN = 128, TO = 64, KC = 16, NN = 512;
    __shared__ float xs[KC][TN];
    __shared__ float wls[KC][TO];
    __shared__ float wus[KC][TO];
    int t = threadIdx.x;
    constexpr int ntiles = NN / TN, otiles = CO2 / TO;
    int bid = blockIdx.x;
    int b = bid / (ntiles * otiles);
    int rem = bid % (ntiles * otiles);
    int n0 = (rem / otiles) * TN;
    int o0 = (rem % otiles) * TO;
    const float* xb = xin + (size_t)b * xbstride;

    int tn = t & 15, to = t >> 4;
    float accG[4][8], accH[4][8];
#pragma unroll
    for (int i = 0; i < 4; i++)
#pragma unroll
        for (int j = 0; j < 8; j++) { accG[i][j] = 0.f; accH[i][j] = 0.f; }

    for (int c0 = 0; c0 < C; c0 += KC) {
        __syncthreads();
        for (int e = t; e < KC * TN; e += 256) {
            int c = e >> 7, n = e & 127;
            xs[c][n] = xb[(size_t)(c0 + c) * NN + n0 + n];
        }
        for (int e = t; e < KC * TO; e += 256) {
            int o = e >> 4, c = e & 15;
            float wl = w1[(size_t)(o0 + o) * (2 * C) + c0 + c];
            float wr = w1[(size_t)(o0 + o) * (2 * C) + C + c0 + c];
            wls[c][o] = wl;
            wus[c][o] = wl + wr;
        }
        __syncthreads();
#pragma unroll 4
        for (int c = 0; c < KC; ++c) {
            float xv[8], wlv[4], wuv[4];
#pragma unroll
            for (int j = 0; j < 8; j++) xv[j] = xs[c][tn + j * 16];
#pragma unroll
            for (int i = 0; i < 4; i++) { wlv[i] = wls[c][to + i * 16]; wuv[i] = wus[c][to + i * 16]; }
#pragma unroll
            for (int i = 0; i < 4; i++)
#pragma unroll
                for (int j = 0; j < 8; j++) {
                    accG[i][j] += wuv[i] * xv[j];
                    accH[i][j] += wlv[i] * xv[j];
                }
        }
    }
#pragma unroll
    for (int i = 0; i < 4; i++) {
        int o = o0 + to + i * 16;
        float bb = b1[o];
#pragma unroll
        for (int j = 0; j < 8; j++) {
            int n = n0 + tn + j * 16;
            size_t off = ((size_t)b * NN + n) * CO2 + o;
            if constexpr (BF16OUT) {
                ((__hip_bfloat16*)Gout)[off] = __float2bfloat16(accG[i][j] + bb);
                ((__hip_bfloat16*)Hout)[off] = __float2bfloat16(accH[i][j]);
            } else {
                ((float*)Gout)[off] = accG[i][j] + bb;
                ((float*)Hout)[off] = accH[i][j];
            }
        }
    }
}

// ---------------------------------------------------------------------------
// Edge-conv pass over G/H: gather h = G[n] - H[m]; STATS accumulates BN
// sums; else BN+leaky -> LDS, second matmul (CO=2*CO2) + max over k.
// ---------------------------------------------------------------------------
template <int CO2, int KK, bool STATS, bool GHBF>
__global__ __launch_bounds__(CO2) void edge2_kernel(
    const void* __restrict__ Gin, const void* __restrict__ Hin,
    const int* __restrict__ idx,
    double* __restrict__ stats,
    const float* __restrict__ scsh, const float* __restrict__ w2,
    const float* __restrict__ b2,
    float* __restrict__ outp, size_t obstride, int tiles_per_block)
{
    constexpr int NN = 512, CCH = 16, TP = 32, TN = TP / KK;
    __shared__ float wtl[STATS ? 1 : CCH][STATS ? 1 : (CO2 + 1)];
    __shared__ float hn[STATS ? 1 : TP * CO2];
    __shared__ int   smidx[TP];
    int t = threadIdx.x;
    float ssum = 0.f, ssq = 0.f;

    for (int ti = 0; ti < tiles_per_block; ++ti) {
        int tileIdx = blockIdx.x * tiles_per_block + ti;
        int b = tileIdx / (NN / TN), nt = tileIdx % (NN / TN);
        int n0 = nt * TN;
        __syncthreads();                    // protect smidx/hn reuse across tiles
        if (t < TP) {
            int n = n0 + t / KK, kk = t % KK;
            smidx[t] = idx[((size_t)(b * NN) + n) * KK + kk];
        }
        __syncthreads();

        float h[TP];
#pragma unroll
        for (int p = 0; p < TP; p++) {
            int n = n0 + p / KK;
            int m = smidx[p];
            size_t go = ((size_t)b * NN + n) * CO2 + t;
            size_t ho = ((size_t)b * NN + m) * CO2 + t;
            float gv, hv;
            if constexpr (GHBF) {
                gv = __bfloat162float(((const __hip_bfloat16*)Gin)[go]);
                hv = __bfloat162float(((const __hip_bfloat16*)Hin)[ho]);
            } else {
                gv = ((const float*)Gin)[go];
                hv = ((const float*)Hin)[ho];
            }
            h[p] = gv - hv;
        }

        if constexpr (STATS) {
#pragma unroll
            for (int p = 0; p < TP; p++) { ssum += h[p]; ssq += h[p] * h[p]; }
        } else {
            float scv = scsh[t], shv = scsh[CO2 + t];
#pragma unroll
            for (int p = 0; p < TP; p++) {
                float v = h[p] * scv + shv;
                hn[p * CO2 + t] = (v >= 0.f) ? v : 0.2f * v;
            }
            for (int g = 0; g < 2; ++g) {
                float s[TP];
#pragma unroll
                for (int p = 0; p < TP; p++) s[p] = 0.f;
                for (int ch = 0; ch < CO2 / CCH; ++ch) {
                    int c0 = ch * CCH;
                    __syncthreads();
                    for (int e = t; e < CCH * CO2; e += CO2) {
                        int o = e / CCH, ci = e % CCH;
                        wtl[ci][o] = w2[((size_t)(g * CO2 + o)) * CO2 + c0 + ci];
                    }
                    __syncthreads();
#pragma unroll
                    for (int c4 = 0; c4 < CCH / 4; c4++) {
                        float a0 = wtl[c4 * 4][t], a1 = wtl[c4 * 4 + 1][t];
                        float a2 = wtl[c4 * 4 + 2][t], a3 = wtl[c4 * 4 + 3][t];
#pragma unroll
                        for (int p = 0; p < TP; p++) {
                            const float4 f = *(const float4*)&hn[p * CO2 + c0 + c4 * 4];
                            s[p] += a0 * f.x + a1 * f.y + a2 * f.z + a3 * f.w;
                        }
                    }
                }
                float bb2 = b2[g * CO2 + t];
#pragma unroll
                for (int nl = 0; nl < TN; ++nl) {
                    float mx = s[nl * KK];
#pragma unroll
                    for (int kk = 1; kk < KK; ++kk) mx = fmaxf(mx, s[nl * KK + kk]);
                    outp[(size_t)b * obstride + (size_t)(g * CO2 + t) * NN + n0 + nl] = mx + bb2;
                }
            }
        }
    }
    if constexpr (STATS) {
        atomicAdd(&stats[t], (double)ssum);
        atomicAdd(&stats[CO2 + t], (double)ssq);
    }
}

// ---------------------------------------------------------------------------
extern "C" void kernel_launch(void* const* d_in, const int* in_sizes, int n_in,
                              void* d_out, int out_size, void* d_ws, size_t ws_size,
                              hipStream_t stream)
{
    const float* x   = (const float*)d_in[0];
    const float* w1a = (const float*)d_in[1];
    const float* b1a = (const float*)d_in[2];
    const float* g1  = (const float*)d_in[3];
    const float* be1 = (const float*)d_in[4];
    const float* w1b = (const float*)d_in[5];
    const float* b1b = (const float*)d_in[6];
    const float* w2a = (const float*)d_in[7];
    const float* b2a = (const float*)d_in[8];
    const float* g2  = (const float*)d_in[9];
    const float* be2 = (const float*)d_in[10];
    const float* w2b = (const float*)d_in[11];
    const float* b2b = (const float*)d_in[12];
    const float* w3a = (const float*)d_in[13];
    const float* b3a = (const float*)d_in[14];
    const float* g3  = (const float*)d_in[15];
    const float* be3 = (const float*)d_in[16];
    const float* w3b = (const float*)d_in[17];
    const float* b3b = (const float*)d_in[18];

    float* out = (float*)d_out;
    float* fws = (float*)d_ws;
    int*    idx1   = (int*)(fws + OFF_IDX1);
    int*    idx2   = (int*)(fws + OFF_IDX2);
    int*    idx3   = (int*)(fws + OFF_IDX3);
    int*    fpsidx = (int*)(fws + OFF_FPS);
    double* st1 = (double*)(fws + OFF_ST);
    double* st2 = st1 + 64;
    double* st3 = st2 + 256;
    float*  ss1 = fws + OFF_SS1;
    float*  ss2 = fws + OFF_SS2;
    float*  ss3 = fws + OFF_SS3;
    double* nrm = (double*)(fws + OFF_NORM);
    float*  x1full = fws + OFF_X1F;
    // multi-use region overlays (lifetimes disjoint):
    float*  G2 = fws + OFF_X1F;                     // fp32 [32][512][128]
    float*  H2 = G2 + 2097152;
    __hip_bfloat16* G3 = (__hip_bfloat16*)(fws + OFF_X1F);          // bf16 [32][512][256]
    __hip_bfloat16* H3 = (__hip_bfloat16*)(fws + OFF_X1F + 2097152);

    const size_t OB = 832 * 512;

    hipMemsetAsync(st1, 0, 832 * sizeof(double), stream);

    // ---- layer 1 ----
    knn3d3_kernel<<<1024, 256, 0, stream>>>(x, idx1);
    stats1_kernel<<<256, 256, 0, stream>>>(x, idx1, w1a, b1a, st1);
    finalize_kernel<<<1, 256, 0, stream>>>(st1, g1, be1, ss1, 32, 1.0 / 1048576.0);
    passB1_kernel<<<4096, 256, 0, stream>>>(x, idx1, w1a, b1a, ss1, w1b, b1b, x1full);

    // ---- fps + gather ----
    fps_kernel<<<32, 64, 0, stream>>>(x, fpsidx);
    gather_kernel<<<4096, 256, 0, stream>>>(x1full, fpsidx, out);
    // x1full dead from here; region reused for G2/H2 then G3/H3.

    // ---- layer 2 (input = out channels [0,64)) ----
    norms_kernel<64><<<64, 256, 0, stream>>>(out, OB, nrm);
    knn_feat2_kernel<64, 8><<<1024, 256, 0, stream>>>(out, OB, nrm, idx2);
    gh_kernel<64, 128, false><<<256, 256, 0, stream>>>(out, OB, w2a, b2a, G2, H2);
    edge2_kernel<128, 8, true, false><<<512, 128, 0, stream>>>(
        G2, H2, idx2, st2, nullptr, nullptr, nullptr, nullptr, 0, 8);
    finalize_kernel<<<1, 256, 0, stream>>>(st2, g2, be2, ss2, 128, 1.0 / 131072.0);
    edge2_kernel<128, 8, false, false><<<4096, 128, 0, stream>>>(
        G2, H2, idx2, nullptr, ss2, w2b, b2b, out + 64 * 512, OB, 1);

    // ---- layer 3 (input = out channels [64,320)) ----
    norms_kernel<256><<<64, 256, 0, stream>>>(out + 64 * 512, OB, nrm);
    knn_feat2_kernel<256, 4><<<1024, 256, 0, stream>>>(out + 64 * 512, OB, nrm, idx3);
    gh_kernel<256, 256, true><<<512, 256, 0, stream>>>(out + 64 * 512, OB, w3a, b3a, G3, H3);
    edge2_kernel<256, 4, true, true><<<512, 256, 0, stream>>>(
        G3, H3, idx3, st3, nullptr, nullptr, nullptr, nullptr, 0, 4);
    finalize_kernel<<<1, 256, 0, stream>>>(st3, g3, be3, ss3, 256, 1.0 / 65536.0);
    edge2_kernel<256, 4, false, true><<<2048, 256, 0, stream>>>(
        G3, H3, idx3, nullptr, ss3, w3b, b3b, out + 320 * 512, OB, 1);
}

// Round 9
// 2475.880 us; speedup vs baseline: 2.4898x; 1.0636x over previous
//
#include <hip/hip_runtime.h>
#include <hip/hip_bf16.h>
#include <cstddef>

// ---------------------------------------------------------------------------
// Problem constants
//   x: (32, 3, 2048) fp32
//   layer1: C=3,  CO2=32,  CO=64,  K=16, N=2048
//   fps -> 512 points; gather x1
//   layer2: C=64, CO2=128, CO=256, K=8,  N=512
//   layer3: C=256,CO2=256, CO=512, K=4,  N=512
//   out: (32, 64+256+512=832, 512) fp32
//
// Edge-conv first matmul via G/H decomposition:
//   h[:,n,k] = G[n] - H[m(n,k)],  G = (W_L+W_R)x + b1,  H = W_L x.
// L2 G/H fp32 (upstream of kNN-3 selection); L3 G/H bf16 (terminal).
// All discrete selections (knn top-k, fps argmax) fp64-exact.
// ---------------------------------------------------------------------------

// ---------------- workspace layout (in float units) ----------------
constexpr size_t OFF_IDX1 = 0;                         // int[32*2048*16]
constexpr size_t OFF_IDX2 = OFF_IDX1 + 1048576;        // int[32*512*8]
constexpr size_t OFF_IDX3 = OFF_IDX2 + 131072;         // int[32*512*4]
constexpr size_t OFF_FPS  = OFF_IDX3 + 65536;          // int[32*512]
constexpr size_t OFF_ST   = OFF_FPS + 16384;           // double[832] = 1664 floats
constexpr size_t OFF_SS1  = OFF_ST + 1664;             // float[64]
constexpr size_t OFF_SS2  = OFF_SS1 + 64;              // float[256]
constexpr size_t OFF_SS3  = OFF_SS2 + 256;             // float[512]
constexpr size_t OFF_NORM = OFF_SS3 + 512;             // double[32*512] = 32768 floats
constexpr size_t OFF_X1F  = OFF_NORM + 32768;          // 4,194,304-float multi-use region

// ---------------------------------------------------------------------------
// Layer-1 kNN (C=3, N=2048, K=16).  64 queries x 4 slices per 256-thr block.
// ---------------------------------------------------------------------------
__global__ __launch_bounds__(256) void knn3d3_kernel(const float* __restrict__ x,
                                                     int* __restrict__ idx)
{
    constexpr int N = 2048, QB = 64, NS = 4, MS = N / NS /*512*/, KK = 16;
    __shared__ __align__(16) double smem[5120];        // 40960 B
    float*  sx  = (float*)smem;                        // [2048]
    float*  sy  = sx + 2048;                           // [2048]
    float*  sz  = sy + 2048;                           // [2048]  (3072 dbl)
    double* snd = smem + 3072;                         // [2048]  (-> 5120 dbl)
    double* mv  = smem;                                // overlay [QB][NS][KK] = 4096 dbl
    unsigned short* mi = (unsigned short*)(smem + 4096); // overlay 2048 u16

    int t = threadIdx.x;
    int q = t >> 2, s = t & 3;
    int b  = blockIdx.x >> 5;
    int n0 = (blockIdx.x & 31) << 6;
    int n  = n0 + q;
    const float* xb = x + (size_t)b * 3 * N;

    for (int e = t; e < N; e += 256) {
        float mx = xb[e], my = xb[N + e], mz = xb[2 * N + e];
        sx[e] = mx; sy[e] = my; sz[e] = mz;
        double dx = (double)mx, dy = (double)my, dz = (double)mz;
        snd[e] = dx * dx + dy * dy + dz * dz;
    }
    __syncthreads();

    double qx = (double)sx[n], qy = (double)sy[n], qz = (double)sz[n];
    double qq = snd[n];
    double bv[KK]; int bi[KK];
#pragma unroll
    for (int j = 0; j < KK; ++j) { bv[j] = -1e300; bi[j] = 0; }

#pragma unroll 4
    for (int i = 0; i < MS; ++i) {
        int mm = (i + s * 8) & (MS - 1);
        int m  = s * MS + mm;
        double dot = qx * (double)sx[m] + qy * (double)sy[m] + qz * (double)sz[m];
        double val = 2.0 * dot - qq - snd[m];
        if (val > bv[KK - 1]) {
            bv[KK - 1] = val; bi[KK - 1] = m;
#pragma unroll
            for (int j = KK - 1; j > 0; --j) {
                if (bv[j] > bv[j - 1]) {
                    double tv = bv[j]; bv[j] = bv[j - 1]; bv[j - 1] = tv;
                    int    ti = bi[j]; bi[j] = bi[j - 1]; bi[j - 1] = ti;
                }
            }
        }
    }
    __syncthreads();
#pragma unroll
    for (int j = 0; j < KK; ++j) {
        mv[(q * NS + s) * KK + j] = bv[j];
        mi[(q * NS + s) * KK + j] = (unsigned short)bi[j];
    }
    __syncthreads();
    if (t < QB) {
        int qq2 = t;
        double hv[NS]; int hj[NS];
#pragma unroll
        for (int s2 = 0; s2 < NS; ++s2) { hv[s2] = mv[(qq2 * NS + s2) * KK]; hj[s2] = 0; }
        int* op = idx + ((size_t)(b * N) + n0 + qq2) * KK;
#pragma unroll
        for (int r = 0; r < KK; ++r) {
            double best = -1e301; int bs = 0;
#pragma unroll
            for (int s2 = 0; s2 < NS; ++s2) {
                if (hv[s2] > best) { best = hv[s2]; bs = s2; }
            }
#pragma unroll
            for (int s2 = 0; s2 < NS; ++s2) {
                if (s2 == bs) {
                    op[r] = (int)mi[(qq2 * NS + s2) * KK + hj[s2]];
                    hj[s2]++;
                    hv[s2] = (hj[s2] < KK) ? mv[(qq2 * NS + s2) * KK + hj[s2]] : -1e301;
                }
            }
        }
    }
}

// ---------------------------------------------------------------------------
// Layer-1 BN statistics
// ---------------------------------------------------------------------------
__global__ __launch_bounds__(256) void stats1_kernel(const float* __restrict__ x,
                                                     const int* __restrict__ idx1,
                                                     const float* __restrict__ w1,
                                                     const float* __restrict__ b1,
                                                     double* __restrict__ stats)
{
    __shared__ float wl[32][9];
    __shared__ float bsh[32];
    __shared__ float red[2][4][32];
    int t = threadIdx.x;
    for (int e = t; e < 192; e += 256) wl[e / 6][e % 6] = w1[e];
    if (t < 32) bsh[t] = b1[t];
    __syncthreads();

    float sum[32], sq[32];
#pragma unroll
    for (int o = 0; o < 32; o++) { sum[o] = 0.f; sq[o] = 0.f; }

    int base = blockIdx.x * 256 + t;
    for (int it = 0; it < 16; ++it) {
        int p = base + it * 65536;
        int b = p >> 15, rem = p & 32767, n = rem >> 4;
        int m = idx1[p];
        const float* xb = x + (size_t)b * 3 * 2048;
        float cx = xb[n], cy = xb[2048 + n], cz = xb[4096 + n];
        float f0 = cx - xb[m], f1 = cy - xb[2048 + m], f2 = cz - xb[4096 + m];
#pragma unroll
        for (int o = 0; o < 32; o++) {
            float h = bsh[o] + wl[o][0] * f0 + wl[o][1] * f1 + wl[o][2] * f2
                             + wl[o][3] * cx + wl[o][4] * cy + wl[o][5] * cz;
            sum[o] += h; sq[o] += h * h;
        }
    }
    int lane = t & 63, wv = t >> 6;
#pragma unroll
    for (int o = 0; o < 32; o++) {
        float s = sum[o], q = sq[o];
#pragma unroll
        for (int d = 1; d < 64; d <<= 1) { s += __shfl_xor(s, d); q += __shfl_xor(q, d); }
        if (lane == 0) { red[0][wv][o] = s; red[1][wv][o] = q; }
    }
    __syncthreads();
    if (t < 32) {
        atomicAdd(&stats[t], (double)(red[0][0][t] + red[0][1][t] + red[0][2][t] + red[0][3][t]));
    } else if (t < 64) {
        int o = t - 32;
        atomicAdd(&stats[32 + o], (double)(red[1][0][o] + red[1][1][o] + red[1][2][o] + red[1][3][o]));
    }
}

// ---------------------------------------------------------------------------
// scale/shift from (sum, sumsq) in fp64
// ---------------------------------------------------------------------------
__global__ void finalize_kernel(const double* __restrict__ stats,
                                const float* __restrict__ g,
                                const float* __restrict__ be,
                                float* __restrict__ scsh, int co2, double invcnt)
{
    int t = threadIdx.x;
    if (t < co2) {
        double mu  = stats[t] * invcnt;
        double var = stats[co2 + t] * invcnt - mu * mu;
        float  sc  = (float)((double)g[t] / sqrt(var + 1e-5));
        scsh[t]       = sc;
        scsh[co2 + t] = be[t] - (float)mu * sc;
    }
}

// ---------------------------------------------------------------------------
// Layer-1 pass B
// ---------------------------------------------------------------------------
__global__ __launch_bounds__(256) void passB1_kernel(const float* __restrict__ x,
                                                     const int* __restrict__ idx1,
                                                     const float* __restrict__ w1,
                                                     const float* __restrict__ b1,
                                                     const float* __restrict__ scsh,
                                                     const float* __restrict__ w2,
                                                     const float* __restrict__ b2,
                                                     float* __restrict__ x1full)
{
    __shared__ float hn[256][36];
    __shared__ float wl[32][9];
    __shared__ float sc[32], sh[32], bs1[32];
    int t = threadIdx.x;
    int b = blockIdx.x >> 7, nt = blockIdx.x & 127;
    int n0 = nt << 4;
    for (int e = t; e < 192; e += 256) wl[e / 6][e % 6] = w1[e];
    if (t < 32) { sc[t] = scsh[t]; sh[t] = scsh[32 + t]; bs1[t] = b1[t]; }
    __syncthreads();
    {
        int n = n0 + (t >> 4), kk = t & 15;
        int pix = (((b << 11) + n) << 4) + kk;
        int m = idx1[pix];
        const float* xb = x + (size_t)b * 3 * 2048;
        float cx = xb[n], cy = xb[2048 + n], cz = xb[4096 + n];
        float f0 = cx - xb[m], f1 = cy - xb[2048 + m], f2 = cz - xb[4096 + m];
#pragma unroll
        for (int o = 0; o < 32; o++) {
            float h = bs1[o] + wl[o][0] * f0 + wl[o][1] * f1 + wl[o][2] * f2
                             + wl[o][3] * cx + wl[o][4] * cy + wl[o][5] * cz;
            h = h * sc[o] + sh[o];
            hn[t][o] = (h >= 0.f) ? h : 0.2f * h;
        }
    }
    __syncthreads();
    int o2 = t & 63, ng = t >> 6;
    float w2r[32];
#pragma unroll
    for (int c = 0; c < 32; c++) w2r[c] = w2[o2 * 32 + c];
    float bb = b2[o2];
#pragma unroll
    for (int ns = 0; ns < 4; ns++) {
        int nl = ng * 4 + ns;
        float mx = -1e30f;
#pragma unroll
        for (int kk = 0; kk < 16; kk++) {
            const float* hp = &hn[(nl << 4) + kk][0];
            float s = 0.f;
#pragma unroll
            for (int c4 = 0; c4 < 8; c4++) {
                float4 f = *(const float4*)(hp + c4 * 4);
                s += w2r[c4 * 4] * f.x + w2r[c4 * 4 + 1] * f.y
                   + w2r[c4 * 4 + 2] * f.z + w2r[c4 * 4 + 3] * f.w;
            }
            mx = fmaxf(mx, s);
        }
        x1full[((size_t)(b << 11) + n0 + nl) * 64 + o2] = mx + bb;
    }
}

// ---------------------------------------------------------------------------
// Farthest point sampling v2 — 4 waves/batch, packed float4 coords, tree
// argmax.  fp64-exact selection, tie -> lowest index (jnp.argmax semantics).
// ---------------------------------------------------------------------------
__global__ __launch_bounds__(256) void fps2_kernel(const float* __restrict__ x,
                                                   int* __restrict__ fpsidx)
{
    constexpr int N = 2048;
    int b = blockIdx.x, t = threadIdx.x;
    int lane = t & 63, wv = t >> 6;
    const float* xb = x + (size_t)b * 3 * N;
    __shared__ __align__(16) float4 sxyz[N];     // 32 KB
    __shared__ double redv[2][4];
    __shared__ int    redi[2][4];

    float px[8], py[8], pz[8];
    double dd[8];
#pragma unroll
    for (int j = 0; j < 8; j++) {
        int n = j * 256 + t;
        float a = xb[n], bb = xb[N + n], c = xb[2 * N + n];
        px[j] = a; py[j] = bb; pz[j] = c; dd[j] = 1e10;   // matches reference init
        sxyz[n] = make_float4(a, bb, c, 0.f);
    }
    __syncthreads();
    if (t == 0) fpsidx[(size_t)b * 512] = 0;
    int last = 0;

    for (int i = 1; i < 512; i++) {
        float4 lp = sxyz[last];                  // single ds_read_b128 broadcast
        double lpx = (double)lp.x, lpy = (double)lp.y, lpz = (double)lp.z;
        double v[8];
#pragma unroll
        for (int j = 0; j < 8; j++) {
            double dx = (double)px[j] - lpx, dy = (double)py[j] - lpy, dz = (double)pz[j] - lpz;
            double d = dx * dx + dy * dy + dz * dz;
            double nd = fmin(dd[j], d);
            dd[j] = nd; v[j] = nd;
        }
        // tree argmax over 8, tie -> lower j (lower n for fixed t)
        double a0 = v[0], a1 = v[1], a2 = v[2], a3 = v[3];
        int    i0 = t,    i1 = 256 + t, i2 = 512 + t, i3 = 768 + t;
        if (v[4] > a0) { a0 = v[4]; i0 = 1024 + t; }
        if (v[5] > a1) { a1 = v[5]; i1 = 1280 + t; }
        if (v[6] > a2) { a2 = v[6]; i2 = 1536 + t; }
        if (v[7] > a3) { a3 = v[7]; i3 = 1792 + t; }
        if (a2 > a0) { a0 = a2; i0 = i2; }
        if (a3 > a1) { a1 = a3; i1 = i3; }
        if (a1 > a0) { a0 = a1; i0 = i1; }
        double bestd = a0; int bestn = i0;
        // wave butterfly (64 lanes), tie -> lower global index
#pragma unroll
        for (int s = 1; s < 64; s <<= 1) {
            double od = __shfl_xor(bestd, s);
            int    on = __shfl_xor(bestn, s);
            if (od > bestd || (od == bestd && on < bestn)) { bestd = od; bestn = on; }
        }
        // cross-wave reduce, double-buffered, one barrier per iteration
        int buf = i & 1;
        if (lane == 0) { redv[buf][wv] = bestd; redi[buf][wv] = bestn; }
        __syncthreads();
        double fb = redv[buf][0]; int fn = redi[buf][0];
#pragma unroll
        for (int w2 = 1; w2 < 4; w2++) {
            double ov = redv[buf][w2]; int on = redi[buf][w2];
            if (ov > fb || (ov == fb && on < fn)) { fb = ov; fn = on; }
        }
        last = fn;
        if (t == 0) fpsidx[(size_t)b * 512 + i] = fn;
    }
}

// ---------------------------------------------------------------------------
// Gather x1 at fps indices into d_out channels [0,64).
// ---------------------------------------------------------------------------
__global__ __launch_bounds__(256) void gather_kernel(const float* __restrict__ x1full,
                                                     const int* __restrict__ fpsidx,
                                                     float* __restrict__ out)
{
    int e = blockIdx.x * 256 + threadIdx.x;
    int j = e & 511; int rest = e >> 9; int c = rest & 63; int b = rest >> 6;
    int fj = fpsidx[b * 512 + j];
    out[((size_t)b * 832 + c) * 512 + j] = x1full[((size_t)(b << 11) + fj) * 64 + c];
}

// ---------------------------------------------------------------------------
// Squared norms per point (fp64).
// ---------------------------------------------------------------------------
template <int C>
__global__ __launch_bounds__(256) void norms_kernel(const float* __restrict__ xin,
                                                    size_t xbstride,
                                                    double* __restrict__ norms)
{
    int b = blockIdx.x >> 1;
    int n = ((blockIdx.x & 1) << 8) + threadIdx.x;
    const float* xb = xin + (size_t)b * xbstride;
    double s = 0.0;
    for (int c = 0; c < C; c++) { double v = (double)xb[(size_t)c * 512 + n]; s += v * v; }
    norms[(b << 9) + n] = s;
}

// ---------------------------------------------------------------------------
// Feature kNN (N=512), 16 queries x 16 slices per block, fp64 exact.
// ---------------------------------------------------------------------------
template <int C, int KK>
__global__ __launch_bounds__(256) void knn_feat2_kernel(const float* __restrict__ xin,
                                                        size_t xbstride,
                                                        const double* __restrict__ norms,
                                                        int* __restrict__ idxout)
{
    constexpr int NN = 512, QB = 16, NS = 16, MS = NN / NS /*32*/, CC = 16;
    constexpr int CHUNKS = C / CC;
    __shared__ __align__(16) double smem[4736];
    float*  sm = (float*)smem;             // [CC][NN]
    float*  sq = (float*)(smem + 4096);    // [CC][QB]
    double* sn = smem + 4224;              // [NN]
    double* mv = smem;                     // overlay [QB][NS][KK]
    int*    mi = (int*)(smem + (size_t)QB * NS * KK);

    int t = threadIdx.x;
    int q = t & 15, s = t >> 4;
    int b  = blockIdx.x >> 5;
    int n0 = (blockIdx.x & 31) << 4;
    int n  = n0 + q;
    const float* xb = xin + (size_t)b * xbstride;

    for (int e = t; e < NN; e += 256) sn[e] = norms[(b << 9) + e];

    double acc[MS];
#pragma unroll
    for (int i = 0; i < MS; ++i) acc[i] = 0.0;

    for (int ch = 0; ch < CHUNKS; ++ch) {
        int c0 = ch * CC;
        __syncthreads();
        for (int e = t; e < CC * NN; e += 256) {
            int c = e >> 9, m = e & 511;
            sm[c * NN + m] = xb[(size_t)(c0 + c) * NN + m];
        }
        {
            int c = t >> 4, qq = t & 15;
            sq[c * QB + qq] = xb[(size_t)(c0 + c) * NN + n0 + qq];
        }
        __syncthreads();
        double qv[CC];
#pragma unroll
        for (int cc = 0; cc < CC; ++cc) qv[cc] = (double)sq[cc * QB + q];
#pragma unroll
        for (int m4 = 0; m4 < MS / 4; ++m4) {
#pragma unroll
            for (int cc = 0; cc < CC; ++cc) {
                float4 f = *(const float4*)&sm[cc * NN + s * MS + m4 * 4];
                acc[m4 * 4 + 0] += qv[cc] * (double)f.x;
                acc[m4 * 4 + 1] += qv[cc] * (double)f.y;
                acc[m4 * 4 + 2] += qv[cc] * (double)f.z;
                acc[m4 * 4 + 3] += qv[cc] * (double)f.w;
            }
        }
    }

    double nq = sn[n];
    double bv[KK]; int bi[KK];
#pragma unroll
    for (int j = 0; j < KK; ++j) { bv[j] = -1e300; bi[j] = 0; }
#pragma unroll
    for (int mm = 0; mm < MS; ++mm) {
        int m = s * MS + mm;
        double val = 2.0 * acc[mm] - nq - sn[m];
        if (val > bv[KK - 1]) {
            bv[KK - 1] = val; bi[KK - 1] = m;
#pragma unroll
            for (int j = KK - 1; j > 0; --j) {
                if (bv[j] > bv[j - 1]) {
                    double tv = bv[j]; bv[j] = bv[j - 1]; bv[j - 1] = tv;
                    int    ti = bi[j]; bi[j] = bi[j - 1]; bi[j - 1] = ti;
                }
            }
        }
    }
    __syncthreads();
#pragma unroll
    for (int j = 0; j < KK; ++j) {
        mv[(q * NS + s) * KK + j] = bv[j];
        mi[(q * NS + s) * KK + j] = bi[j];
    }
    __syncthreads();
    if (t < QB) {
        int qq2 = t;
        double hv[NS]; int hj[NS];
#pragma unroll
        for (int s2 = 0; s2 < NS; ++s2) { hv[s2] = mv[(qq2 * NS + s2) * KK]; hj[s2] = 0; }
        int* op = idxout + ((size_t)(b * NN) + n0 + qq2) * KK;
#pragma unroll
        for (int r = 0; r < KK; ++r) {
            double best = -1e301; int bs = 0;
#pragma unroll
            for (int s2 = 0; s2 < NS; ++s2) {
                if (hv[s2] > best) { best = hv[s2]; bs = s2; }
            }
#pragma unroll
            for (int s2 = 0; s2 < NS; ++s2) {
                if (s2 == bs) {
                    op[r] = mi[(qq2 * NS + s2) * KK + hj[s2]];
                    hj[s2]++;
                    hv[s2] = (hj[s2] < KK) ? mv[(qq2 * NS + s2) * KK + hj[s2]] : -1e301;
                }
            }
        }
    }
}

// ---------------------------------------------------------------------------
// G/H precompute GEMM.
// ---------------------------------------------------------------------------
template <int C, int CO2, bool BF16OUT>
__global__ __launch_bounds__(256) void gh_kernel(const float* __restrict__ xin,
                                                 size_t xbstride,
                                                 const float* __restrict__ w1,
                                                 const float* __restrict__ b1,
                                                 void* __restrict__ Gout,
                                                 void* __restrict__ Hout)
{
    constexpr int TN = 128, TO = 64, KC = 16, NN = 512;
    __shared__ float xs[KC][TN];
    __shared__ float wls[KC][TO];
    __shared__ float wus[KC][TO];
    int t = threadIdx.x;
    constexpr int ntiles = NN / TN, otiles = CO2 / TO;
    int bid = blockIdx.x;
    int b = bid / (ntiles * otiles);
    int rem = bid % (ntiles * otiles);
    int n0 = (rem / otiles) * TN;
    int o0 = (rem % otiles) * TO;
    const float* xb = xin + (size_t)b * xbstride;

    int tn = t & 15, to = t >> 4;
    float accG[4][8], accH[4][8];
#pragma unroll
    for (int i = 0; i < 4; i++)
#pragma unroll
        for (int j = 0; j < 8; j++) { accG[i][j] = 0.f; accH[i][j] = 0.f; }

    for (int c0 = 0; c0 < C; c0 += KC) {
        __syncthreads();
        for (int e = t; e < KC * TN; e += 256) {
            int c = e >> 7, n = e & 127;
            xs[c][n] = xb[(size_t)(c0 + c) * NN + n0 + n];
        }
        for (int e = t; e < KC * TO; e += 256) {
            int o = e >> 4, c = e & 15;
            float wl = w1[(size_t)(o0 + o) * (2 * C) + c0 + c];
            float wr = w1[(size_t)(o0 + o) * (2 * C) + C + c0 + c];
            wls[c][o] = wl;
            wus[c][o] = wl + wr;
        }
        __syncthreads();
#pragma unroll 4
        for (int c = 0; c < KC; ++c) {
            float xv[8], wlv[4], wuv[4];
#pragma unroll
            for (int j = 0; j < 8; j++) xv[j] = xs[c][tn + j * 16];
#pragma unroll
            for (int i = 0; i < 4; i++) { wlv[i] = wls[c][to + i * 16]; wuv[i] = wus[c][to + i * 16]; }
#pragma unroll
            for (int i = 0; i < 4; i++)
#pragma unroll
                for (int j = 0; j < 8; j++) {
                    accG[i][j] += wuv[i] * xv[j];
                    accH[i][j] += wlv[i] * xv[j];
                }
        }
    }
#pragma unroll
    for (int i = 0; i < 4; i++) {
        int o = o0 + to + i * 16;
        float bb = b1[o];
#pragma unroll
        for (int j = 0; j < 8; j++) {
            int n = n0 + tn + j * 16;
            size_t off = ((size_t)b * NN + n) * CO2 + o;
            if constexpr (BF16OUT) {
                ((__hip_bfloat16*)Gout)[off] = __float2bfloat16(accG[i][j] + bb);
                ((__hip_bfloat16*)Hout)[off] = __float2bfloat16(accH[i][j]);
            } else {
                ((float*)Gout)[off] = accG[i][j] + bb;
                ((float*)Hout)[off] = accH[i][j];
            }
        }
    }
}

// ---------------------------------------------------------------------------
// Edge-conv pass over G/H.
// ---------------------------------------------------------------------------
template <int CO2, int KK, bool STATS, bool GHBF>
__global__ __launch_bounds__(CO2) void edge2_kernel(
    const void* __restrict__ Gin, const void* __restrict__ Hin,
    const int* __restrict__ idx,
    double* __restrict__ stats,
    const float* __restrict__ scsh, const float* __restrict__ w2,
    const float* __restrict__ b2,
    float* __restrict__ outp, size_t obstride, int tiles_per_block)
{
    constexpr int NN = 512, CCH = 16, TP = 32, TN = TP / KK;
    __shared__ float wtl[STATS ? 1 : CCH][STATS ? 1 : (CO2 + 1)];
    __shared__ float hn[STATS ? 1 : TP * CO2];
    __shared__ int   smidx[TP];
    int t = threadIdx.x;
    float ssum = 0.f, ssq = 0.f;

    for (int ti = 0; ti < tiles_per_block; ++ti) {
        int tileIdx = blockIdx.x * tiles_per_block + ti;
        int b = tileIdx / (NN / TN), nt = tileIdx % (NN / TN);
        int n0 = nt * TN;
        __syncthreads();
        if (t < TP) {
            int n = n0 + t / KK, kk = t % KK;
            smidx[t] = idx[((size_t)(b * NN) + n) * KK + kk];
        }
        __syncthreads();

        float h[TP];
#pragma unroll
        for (int p = 0; p < TP; p++) {
            int n = n0 + p / KK;
            int m = smidx[p];
            size_t go = ((size_t)b * NN + n) * CO2 + t;
            size_t ho = ((size_t)b * NN + m) * CO2 + t;
            float gv, hv;
            if constexpr (GHBF) {
                gv = __bfloat162float(((const __hip_bfloat16*)Gin)[go]);
                hv = __bfloat162float(((const __hip_bfloat16*)Hin)[ho]);
            } else {
                gv = ((const float*)Gin)[go];
                hv = ((const float*)Hin)[ho];
            }
            h[p] = gv - hv;
        }

        if constexpr (STATS) {
#pragma unroll
            for (int p = 0; p < TP; p++) { ssum += h[p]; ssq += h[p] * h[p]; }
        } else {
            float scv = scsh[t], shv = scsh[CO2 + t];
#pragma unroll
            for (int p = 0; p < TP; p++) {
                float v = h[p] * scv + shv;
                hn[p * CO2 + t] = (v >= 0.f) ? v : 0.2f * v;
            }
            for (int g = 0; g < 2; ++g) {
                float s[TP];
#pragma unroll
                for (int p = 0; p < TP; p++) s[p] = 0.f;
                for (int ch = 0; ch < CO2 / CCH; ++ch) {
                    int c0 = ch * CCH;
                    __syncthreads();
                    for (int e = t; e < CCH * CO2; e += CO2) {
                        int o = e / CCH, ci = e % CCH;
                        wtl[ci][o] = w2[((size_t)(g * CO2 + o)) * CO2 + c0 + ci];
                    }
                    __syncthreads();
#pragma unroll
                    for (int c4 = 0; c4 < CCH / 4; c4++) {
                        float a0 = wtl[c4 * 4][t], a1 = wtl[c4 * 4 + 1][t];
                        float a2 = wtl[c4 * 4 + 2][t], a3 = wtl[c4 * 4 + 3][t];
#pragma unroll
                        for (int p = 0; p < TP; p++) {
                            const float4 f = *(const float4*)&hn[p * CO2 + c0 + c4 * 4];
                            s[p] += a0 * f.x + a1 * f.y + a2 * f.z + a3 * f.w;
                        }
                    }
                }
                float bb2 = b2[g * CO2 + t];
#pragma unroll
                for (int nl = 0; nl < TN; ++nl) {
                    float mx = s[nl * KK];
#pragma unroll
                    for (int kk = 1; kk < KK; ++kk) mx = fmaxf(mx, s[nl * KK + kk]);
                    outp[(size_t)b * obstride + (size_t)(g * CO2 + t) * NN + n0 + nl] = mx + bb2;
                }
            }
        }
    }
    if constexpr (STATS) {
        atomicAdd(&stats[t], (double)ssum);
        atomicAdd(&stats[CO2 + t], (double)ssq);
    }
}

// ---------------------------------------------------------------------------
extern "C" void kernel_launch(void* const* d_in, const int* in_sizes, int n_in,
                              void* d_out, int out_size, void* d_ws, size_t ws_size,
                              hipStream_t stream)
{
    const float* x   = (const float*)d_in[0];
    const float* w1a = (const float*)d_in[1];
    const float* b1a = (const float*)d_in[2];
    const float* g1  = (const float*)d_in[3];
    const float* be1 = (const float*)d_in[4];
    const float* w1b = (const float*)d_in[5];
    const float* b1b = (const float*)d_in[6];
    const float* w2a = (const float*)d_in[7];
    const float* b2a = (const float*)d_in[8];
    const float* g2  = (const float*)d_in[9];
    const float* be2 = (const float*)d_in[10];
    const float* w2b = (const float*)d_in[11];
    const float* b2b = (const float*)d_in[12];
    const float* w3a = (const float*)d_in[13];
    const float* b3a = (const float*)d_in[14];
    const float* g3  = (const float*)d_in[15];
    const float* be3 = (const float*)d_in[16];
    const float* w3b = (const float*)d_in[17];
    const float* b3b = (const float*)d_in[18];

    float* out = (float*)d_out;
    float* fws = (float*)d_ws;
    int*    idx1   = (int*)(fws + OFF_IDX1);
    int*    idx2   = (int*)(fws + OFF_IDX2);
    int*    idx3   = (int*)(fws + OFF_IDX3);
    int*    fpsidx = (int*)(fws + OFF_FPS);
    double* st1 = (double*)(fws + OFF_ST);
    double* st2 = st1 + 64;
    double* st3 = st2 + 256;
    float*  ss1 = fws + OFF_SS1;
    float*  ss2 = fws + OFF_SS2;
    float*  ss3 = fws + OFF_SS3;
    double* nrm = (double*)(fws + OFF_NORM);
    float*  x1full = fws + OFF_X1F;
    float*  G2 = fws + OFF_X1F;
    float*  H2 = G2 + 2097152;
    __hip_bfloat16* G3 = (__hip_bfloat16*)(fws + OFF_X1F);
    __hip_bfloat16* H3 = (__hip_bfloat16*)(fws + OFF_X1F + 2097152);

    const size_t OB = 832 * 512;

    hipMemsetAsync(st1, 0, 832 * sizeof(double), stream);

    // ---- layer 1 ----
    knn3d3_kernel<<<1024, 256, 0, stream>>>(x, idx1);
    stats1_kernel<<<256, 256, 0, stream>>>(x, idx1, w1a, b1a, st1);
    finalize_kernel<<<1, 256, 0, stream>>>(st1, g1, be1, ss1, 32, 1.0 / 1048576.0);
    passB1_kernel<<<4096, 256, 0, stream>>>(x, idx1, w1a, b1a, ss1, w1b, b1b, x1full);

    // ---- fps + gather ----
    fps2_kernel<<<32, 256, 0, stream>>>(x, fpsidx);
    gather_kernel<<<4096, 256, 0, stream>>>(x1full, fpsidx, out);
    // x1full dead from here; region reused for G2/H2 then G3/H3.

    // ---- layer 2 (input = out channels [0,64)) ----
    norms_kernel<64><<<64, 256, 0, stream>>>(out, OB, nrm);
    knn_feat2_kernel<64, 8><<<1024, 256, 0, stream>>>(out, OB, nrm, idx2);
    gh_kernel<64, 128, false><<<256, 256, 0, stream>>>(out, OB, w2a, b2a, G2, H2);
    edge2_kernel<128, 8, true, false><<<512, 128, 0, stream>>>(
        G2, H2, idx2, st2, nullptr, nullptr, nullptr, nullptr, 0, 8);
    finalize_kernel<<<1, 256, 0, stream>>>(st2, g2, be2, ss2, 128, 1.0 / 131072.0);
    edge2_kernel<128, 8, false, false><<<4096, 128, 0, stream>>>(
        G2, H2, idx2, nullptr, ss2, w2b, b2b, out + 64 * 512, OB, 1);

    // ---- layer 3 (input = out channels [64,320)) ----
    norms_kernel<256><<<64, 256, 0, stream>>>(out + 64 * 512, OB, nrm);
    knn_feat2_kernel<256, 4><<<1024, 256, 0, stream>>>(out + 64 * 512, OB, nrm, idx3);
    gh_kernel<256, 256, true><<<512, 256, 0, stream>>>(out + 64 * 512, OB, w3a, b3a, G3, H3);
    edge2_kernel<256, 4, true, true><<<512, 256, 0, stream>>>(
        G3, H3, idx3, st3, nullptr, nullptr, nullptr, nullptr, 0, 4);
    finalize_kernel<<<1, 256, 0, stream>>>(st3, g3, be3, ss3, 256, 1.0 / 65536.0);
    edge2_kernel<256, 4, false, true><<<2048, 256, 0, stream>>>(
        G3, H3, idx3, nullptr, ss3, w3b, b3b, out + 320 * 512, OB, 1);
}

// Round 10
// 2109.552 us; speedup vs baseline: 2.9222x; 1.1737x over previous
//
#include <hip/hip_runtime.h>
#include <hip/hip_bf16.h>
#include <cstddef>

// ---------------------------------------------------------------------------
// Problem constants
//   x: (32, 3, 2048) fp32
//   layer1: C=3,  CO2=32,  CO=64,  K=16, N=2048
//   fps -> 512 points; gather x1
//   layer2: C=64, CO2=128, CO=256, K=8,  N=512
//   layer3: C=256,CO2=256, CO=512, K=4,  N=512
//   out: (32, 64+256+512=832, 512) fp32
//
// Edge-conv first matmul via G/H decomposition:
//   h[:,n,k] = G[n] - H[m(n,k)],  G = (W_L+W_R)x + b1,  H = W_L x.
// L2 G/H fp32 (upstream of kNN-3 selection); L3 G/H bf16 (terminal).
// L3 second conv: bf16 MFMA (terminal layer, fp32 accumulate).
// All discrete selections (knn top-k, fps argmax) fp64-exact.
// ---------------------------------------------------------------------------

typedef __bf16 bf16x8 __attribute__((ext_vector_type(8)));
typedef float  f32x4  __attribute__((ext_vector_type(4)));

// ---------------- workspace layout (in float units) ----------------
constexpr size_t OFF_IDX1 = 0;                         // int[32*2048*16]
constexpr size_t OFF_IDX2 = OFF_IDX1 + 1048576;        // int[32*512*8]
constexpr size_t OFF_IDX3 = OFF_IDX2 + 131072;         // int[32*512*4]
constexpr size_t OFF_FPS  = OFF_IDX3 + 65536;          // int[32*512]
constexpr size_t OFF_ST   = OFF_FPS + 16384;           // double[832] = 1664 floats
constexpr size_t OFF_SS1  = OFF_ST + 1664;             // float[64]
constexpr size_t OFF_SS2  = OFF_SS1 + 64;              // float[256]
constexpr size_t OFF_SS3  = OFF_SS2 + 256;             // float[512]
constexpr size_t OFF_NORM = OFF_SS3 + 512;             // double[32*512] = 32768 floats
constexpr size_t OFF_X1F  = OFF_NORM + 32768;          // 4,194,304-float multi-use region
constexpr size_t OFF_W3BF = OFF_X1F + 4194304;         // bf16[512*256] = 65536 floats

// ---------------------------------------------------------------------------
// Layer-1 kNN (C=3, N=2048, K=16).  64 queries x 4 slices per 256-thr block.
// ---------------------------------------------------------------------------
__global__ __launch_bounds__(256) void knn3d3_kernel(const float* __restrict__ x,
                                                     int* __restrict__ idx)
{
    constexpr int N = 2048, QB = 64, NS = 4, MS = N / NS /*512*/, KK = 16;
    __shared__ __align__(16) double smem[5120];        // 40960 B
    float*  sx  = (float*)smem;                        // [2048]
    float*  sy  = sx + 2048;                           // [2048]
    float*  sz  = sy + 2048;                           // [2048]  (3072 dbl)
    double* snd = smem + 3072;                         // [2048]  (-> 5120 dbl)
    double* mv  = smem;                                // overlay [QB][NS][KK] = 4096 dbl
    unsigned short* mi = (unsigned short*)(smem + 4096); // overlay 2048 u16

    int t = threadIdx.x;
    int q = t >> 2, s = t & 3;
    int b  = blockIdx.x >> 5;
    int n0 = (blockIdx.x & 31) << 6;
    int n  = n0 + q;
    const float* xb = x + (size_t)b * 3 * N;

    for (int e = t; e < N; e += 256) {
        float mx = xb[e], my = xb[N + e], mz = xb[2 * N + e];
        sx[e] = mx; sy[e] = my; sz[e] = mz;
        double dx = (double)mx, dy = (double)my, dz = (double)mz;
        snd[e] = dx * dx + dy * dy + dz * dz;
    }
    __syncthreads();

    double qx = (double)sx[n], qy = (double)sy[n], qz = (double)sz[n];
    double qq = snd[n];
    double bv[KK]; int bi[KK];
#pragma unroll
    for (int j = 0; j < KK; ++j) { bv[j] = -1e300; bi[j] = 0; }

#pragma unroll 4
    for (int i = 0; i < MS; ++i) {
        int mm = (i + s * 8) & (MS - 1);
        int m  = s * MS + mm;
        double dot = qx * (double)sx[m] + qy * (double)sy[m] + qz * (double)sz[m];
        double val = 2.0 * dot - qq - snd[m];
        if (val > bv[KK - 1]) {
            bv[KK - 1] = val; bi[KK - 1] = m;
#pragma unroll
            for (int j = KK - 1; j > 0; --j) {
                if (bv[j] > bv[j - 1]) {
                    double tv = bv[j]; bv[j] = bv[j - 1]; bv[j - 1] = tv;
                    int    ti = bi[j]; bi[j] = bi[j - 1]; bi[j - 1] = ti;
                }
            }
        }
    }
    __syncthreads();
#pragma unroll
    for (int j = 0; j < KK; ++j) {
        mv[(q * NS + s) * KK + j] = bv[j];
        mi[(q * NS + s) * KK + j] = (unsigned short)bi[j];
    }
    __syncthreads();
    if (t < QB) {
        int qq2 = t;
        double hv[NS]; int hj[NS];
#pragma unroll
        for (int s2 = 0; s2 < NS; ++s2) { hv[s2] = mv[(qq2 * NS + s2) * KK]; hj[s2] = 0; }
        int* op = idx + ((size_t)(b * N) + n0 + qq2) * KK;
#pragma unroll
        for (int r = 0; r < KK; ++r) {
            double best = -1e301; int bs = 0;
#pragma unroll
            for (int s2 = 0; s2 < NS; ++s2) {
                if (hv[s2] > best) { best = hv[s2]; bs = s2; }
            }
#pragma unroll
            for (int s2 = 0; s2 < NS; ++s2) {
                if (s2 == bs) {
                    op[r] = (int)mi[(qq2 * NS + s2) * KK + hj[s2]];
                    hj[s2]++;
                    hv[s2] = (hj[s2] < KK) ? mv[(qq2 * NS + s2) * KK + hj[s2]] : -1e301;
                }
            }
        }
    }
}

// ---------------------------------------------------------------------------
// Layer-1 BN statistics
// ---------------------------------------------------------------------------
__global__ __launch_bounds__(256) void stats1_kernel(const float* __restrict__ x,
                                                     const int* __restrict__ idx1,
                                                     const float* __restrict__ w1,
                                                     const float* __restrict__ b1,
                                                     double* __restrict__ stats)
{
    __shared__ float wl[32][9];
    __shared__ float bsh[32];
    __shared__ float red[2][4][32];
    int t = threadIdx.x;
    for (int e = t; e < 192; e += 256) wl[e / 6][e % 6] = w1[e];
    if (t < 32) bsh[t] = b1[t];
    __syncthreads();

    float sum[32], sq[32];
#pragma unroll
    for (int o = 0; o < 32; o++) { sum[o] = 0.f; sq[o] = 0.f; }

    int base = blockIdx.x * 256 + t;
    for (int it = 0; it < 16; ++it) {
        int p = base + it * 65536;
        int b = p >> 15, rem = p & 32767, n = rem >> 4;
        int m = idx1[p];
        const float* xb = x + (size_t)b * 3 * 2048;
        float cx = xb[n], cy = xb[2048 + n], cz = xb[4096 + n];
        float f0 = cx - xb[m], f1 = cy - xb[2048 + m], f2 = cz - xb[4096 + m];
#pragma unroll
        for (int o = 0; o < 32; o++) {
            float h = bsh[o] + wl[o][0] * f0 + wl[o][1] * f1 + wl[o][2] * f2
                             + wl[o][3] * cx + wl[o][4] * cy + wl[o][5] * cz;
            sum[o] += h; sq[o] += h * h;
        }
    }
    int lane = t & 63, wv = t >> 6;
#pragma unroll
    for (int o = 0; o < 32; o++) {
        float s = sum[o], q = sq[o];
#pragma unroll
        for (int d = 1; d < 64; d <<= 1) { s += __shfl_xor(s, d); q += __shfl_xor(q, d); }
        if (lane == 0) { red[0][wv][o] = s; red[1][wv][o] = q; }
    }
    __syncthreads();
    if (t < 32) {
        atomicAdd(&stats[t], (double)(red[0][0][t] + red[0][1][t] + red[0][2][t] + red[0][3][t]));
    } else if (t < 64) {
        int o = t - 32;
        atomicAdd(&stats[32 + o], (double)(red[1][0][o] + red[1][1][o] + red[1][2][o] + red[1][3][o]));
    }
}

// ---------------------------------------------------------------------------
// scale/shift from (sum, sumsq) in fp64
// ---------------------------------------------------------------------------
__global__ void finalize_kernel(const double* __restrict__ stats,
                                const float* __restrict__ g,
                                const float* __restrict__ be,
                                float* __restrict__ scsh, int co2, double invcnt)
{
    int t = threadIdx.x;
    if (t < co2) {
        double mu  = stats[t] * invcnt;
        double var = stats[co2 + t] * invcnt - mu * mu;
        float  sc  = (float)((double)g[t] / sqrt(var + 1e-5));
        scsh[t]       = sc;
        scsh[co2 + t] = be[t] - (float)mu * sc;
    }
}

// ---------------------------------------------------------------------------
// fp32 -> bf16 convert (for w3b weights)
// ---------------------------------------------------------------------------
__global__ __launch_bounds__(256) void cvt_bf16_kernel(const float* __restrict__ src,
                                                       __hip_bfloat16* __restrict__ dst,
                                                       int n)
{
    int i = blockIdx.x * 256 + threadIdx.x;
    if (i < n) dst[i] = __float2bfloat16(src[i]);
}

// ---------------------------------------------------------------------------
// Layer-1 pass B
// ---------------------------------------------------------------------------
__global__ __launch_bounds__(256) void passB1_kernel(const float* __restrict__ x,
                                                     const int* __restrict__ idx1,
                                                     const float* __restrict__ w1,
                                                     const float* __restrict__ b1,
                                                     const float* __restrict__ scsh,
                                                     const float* __restrict__ w2,
                                                     const float* __restrict__ b2,
                                                     float* __restrict__ x1full)
{
    __shared__ float hn[256][36];
    __shared__ float wl[32][9];
    __shared__ float sc[32], sh[32], bs1[32];
    int t = threadIdx.x;
    int b = blockIdx.x >> 7, nt = blockIdx.x & 127;
    int n0 = nt << 4;
    for (int e = t; e < 192; e += 256) wl[e / 6][e % 6] = w1[e];
    if (t < 32) { sc[t] = scsh[t]; sh[t] = scsh[32 + t]; bs1[t] = b1[t]; }
    __syncthreads();
    {
        int n = n0 + (t >> 4), kk = t & 15;
        int pix = (((b << 11) + n) << 4) + kk;
        int m = idx1[pix];
        const float* xb = x + (size_t)b * 3 * 2048;
        float cx = xb[n], cy = xb[2048 + n], cz = xb[4096 + n];
        float f0 = cx - xb[m], f1 = cy - xb[2048 + m], f2 = cz - xb[4096 + m];
#pragma unroll
        for (int o = 0; o < 32; o++) {
            float h = bs1[o] + wl[o][0] * f0 + wl[o][1] * f1 + wl[o][2] * f2
                             + wl[o][3] * cx + wl[o][4] * cy + wl[o][5] * cz;
            h = h * sc[o] + sh[o];
            hn[t][o] = (h >= 0.f) ? h : 0.2f * h;
        }
    }
    __syncthreads();
    int o2 = t & 63, ng = t >> 6;
    float w2r[32];
#pragma unroll
    for (int c = 0; c < 32; c++) w2r[c] = w2[o2 * 32 + c];
    float bb = b2[o2];
#pragma unroll
    for (int ns = 0; ns < 4; ns++) {
        int nl = ng * 4 + ns;
        float mx = -1e30f;
#pragma unroll
        for (int kk = 0; kk < 16; kk++) {
            const float* hp = &hn[(nl << 4) + kk][0];
            float s = 0.f;
#pragma unroll
            for (int c4 = 0; c4 < 8; c4++) {
                float4 f = *(const float4*)(hp + c4 * 4);
                s += w2r[c4 * 4] * f.x + w2r[c4 * 4 + 1] * f.y
                   + w2r[c4 * 4 + 2] * f.z + w2r[c4 * 4 + 3] * f.w;
            }
            mx = fmaxf(mx, s);
        }
        x1full[((size_t)(b << 11) + n0 + nl) * 64 + o2] = mx + bb;
    }
}

// ---------------------------------------------------------------------------
// Farthest point sampling v2 — 4 waves/batch, packed float4 coords, tree
// argmax.  fp64-exact selection, tie -> lowest index (jnp.argmax semantics).
// ---------------------------------------------------------------------------
__global__ __launch_bounds__(256) void fps2_kernel(const float* __restrict__ x,
                                                   int* __restrict__ fpsidx)
{
    constexpr int N = 2048;
    int b = blockIdx.x, t = threadIdx.x;
    int lane = t & 63, wv = t >> 6;
    const float* xb = x + (size_t)b * 3 * N;
    __shared__ __align__(16) float4 sxyz[N];     // 32 KB
    __shared__ double redv[2][4];
    __shared__ int    redi[2][4];

    float px[8], py[8], pz[8];
    double dd[8];
#pragma unroll
    for (int j = 0; j < 8; j++) {
        int n = j * 256 + t;
        float a = xb[n], bb = xb[N + n], c = xb[2 * N + n];
        px[j] = a; py[j] = bb; pz[j] = c; dd[j] = 1e10;
        sxyz[n] = make_float4(a, bb, c, 0.f);
    }
    __syncthreads();
    if (t == 0) fpsidx[(size_t)b * 512] = 0;
    int last = 0;

    for (int i = 1; i < 512; i++) {
        float4 lp = sxyz[last];
        double lpx = (double)lp.x, lpy = (double)lp.y, lpz = (double)lp.z;
        double v[8];
#pragma unroll
        for (int j = 0; j < 8; j++) {
            double dx = (double)px[j] - lpx, dy = (double)py[j] - lpy, dz = (double)pz[j] - lpz;
            double d = dx * dx + dy * dy + dz * dz;
            double nd = fmin(dd[j], d);
            dd[j] = nd; v[j] = nd;
        }
        double a0 = v[0], a1 = v[1], a2 = v[2], a3 = v[3];
        int    i0 = t,    i1 = 256 + t, i2 = 512 + t, i3 = 768 + t;
        if (v[4] > a0) { a0 = v[4]; i0 = 1024 + t; }
        if (v[5] > a1) { a1 = v[5]; i1 = 1280 + t; }
        if (v[6] > a2) { a2 = v[6]; i2 = 1536 + t; }
        if (v[7] > a3) { a3 = v[7]; i3 = 1792 + t; }
        if (a2 > a0) { a0 = a2; i0 = i2; }
        if (a3 > a1) { a1 = a3; i1 = i3; }
        if (a1 > a0) { a0 = a1; i0 = i1; }
        double bestd = a0; int bestn = i0;
#pragma unroll
        for (int s = 1; s < 64; s <<= 1) {
            double od = __shfl_xor(bestd, s);
            int    on = __shfl_xor(bestn, s);
            if (od > bestd || (od == bestd && on < bestn)) { bestd = od; bestn = on; }
        }
        int buf = i & 1;
        if (lane == 0) { redv[buf][wv] = bestd; redi[buf][wv] = bestn; }
        __syncthreads();
        double fb = redv[buf][0]; int fn = redi[buf][0];
#pragma unroll
        for (int w2 = 1; w2 < 4; w2++) {
            double ov = redv[buf][w2]; int on = redi[buf][w2];
            if (ov > fb || (ov == fb && on < fn)) { fb = ov; fn = on; }
        }
        last = fn;
        if (t == 0) fpsidx[(size_t)b * 512 + i] = fn;
    }
}

// ---------------------------------------------------------------------------
// Gather x1 at fps indices into d_out channels [0,64).
// ---------------------------------------------------------------------------
__global__ __launch_bounds__(256) void gather_kernel(const float* __restrict__ x1full,
                                                     const int* __restrict__ fpsidx,
                                                     float* __restrict__ out)
{
    int e = blockIdx.x * 256 + threadIdx.x;
    int j = e & 511; int rest = e >> 9; int c = rest & 63; int b = rest >> 6;
    int fj = fpsidx[b * 512 + j];
    out[((size_t)b * 832 + c) * 512 + j] = x1full[((size_t)(b << 11) + fj) * 64 + c];
}

// ---------------------------------------------------------------------------
// Squared norms per point (fp64).
// ---------------------------------------------------------------------------
template <int C>
__global__ __launch_bounds__(256) void norms_kernel(const float* __restrict__ xin,
                                                    size_t xbstride,
                                                    double* __restrict__ norms)
{
    int b = blockIdx.x >> 1;
    int n = ((blockIdx.x & 1) << 8) + threadIdx.x;
    const float* xb = xin + (size_t)b * xbstride;
    double s = 0.0;
    for (int c = 0; c < C; c++) { double v = (double)xb[(size_t)c * 512 + n]; s += v * v; }
    norms[(b << 9) + n] = s;
}

// ---------------------------------------------------------------------------
// Feature kNN (N=512), 16 queries x 16 slices per block, fp64 exact.
// ---------------------------------------------------------------------------
template <int C, int KK>
__global__ __launch_bounds__(256) void knn_feat2_kernel(const float* __restrict__ xin,
                                                        size_t xbstride,
                                                        const double* __restrict__ norms,
                                                        int* __restrict__ idxout)
{
    constexpr int NN = 512, QB = 16, NS = 16, MS = NN / NS /*32*/, CC = 16;
    constexpr int CHUNKS = C / CC;
    __shared__ __align__(16) double smem[4736];
    float*  sm = (float*)smem;             // [CC][NN]
    float*  sq = (float*)(smem + 4096);    // [CC][QB]
    double* sn = smem + 4224;              // [NN]
    double* mv = smem;                     // overlay [QB][NS][KK]
    int*    mi = (int*)(smem + (size_t)QB * NS * KK);

    int t = threadIdx.x;
    int q = t & 15, s = t >> 4;
    int b  = blockIdx.x >> 5;
    int n0 = (blockIdx.x & 31) << 4;
    int n  = n0 + q;
    const float* xb = xin + (size_t)b * xbstride;

    for (int e = t; e < NN; e += 256) sn[e] = norms[(b << 9) + e];

    double acc[MS];
#pragma unroll
    for (int i = 0; i < MS; ++i) acc[i] = 0.0;

    for (int ch = 0; ch < CHUNKS; ++ch) {
        int c0 = ch * CC;
        __syncthreads();
        for (int e = t; e < CC * NN; e += 256) {
            int c = e >> 9, m = e & 511;
            sm[c * NN + m] = xb[(size_t)(c0 + c) * NN + m];
        }
        {
            int c = t >> 4, qq = t & 15;
            sq[c * QB + qq] = xb[(size_t)(c0 + c) * NN + n0 + qq];
        }
        __syncthreads();
        double qv[CC];
#pragma unroll
        for (int cc = 0; cc < CC; ++cc) qv[cc] = (double)sq[cc * QB + q];
#pragma unroll
        for (int m4 = 0; m4 < MS / 4; ++m4) {
#pragma unroll
            for (int cc = 0; cc < CC; ++cc) {
                float4 f = *(const float4*)&sm[cc * NN + s * MS + m4 * 4];
                acc[m4 * 4 + 0] += qv[cc] * (double)f.x;
                acc[m4 * 4 + 1] += qv[cc] * (double)f.y;
                acc[m4 * 4 + 2] += qv[cc] * (double)f.z;
                acc[m4 * 4 + 3] += qv[cc] * (double)f.w;
            }
        }
    }

    double nq = sn[n];
    double bv[KK]; int bi[KK];
#pragma unroll
    for (int j = 0; j < KK; ++j) { bv[j] = -1e300; bi[j] = 0; }
#pragma unroll
    for (int mm = 0; mm < MS; ++mm) {
        int m = s * MS + mm;
        double val = 2.0 * acc[mm] - nq - sn[m];
        if (val > bv[KK - 1]) {
            bv[KK - 1] = val; bi[KK - 1] = m;
#pragma unroll
            for (int j = KK - 1; j > 0; --j) {
                if (bv[j] > bv[j - 1]) {
                    double tv = bv[j]; bv[j] = bv[j - 1]; bv[j - 1] = tv;
                    int    ti = bi[j]; bi[j] = bi[j - 1]; bi[j - 1] = ti;
                }
            }
        }
    }
    __syncthreads();
#pragma unroll
    for (int j = 0; j < KK; ++j) {
        mv[(q * NS + s) * KK + j] = bv[j];
        mi[(q * NS + s) * KK + j] = bi[j];
    }
    __syncthreads();
    if (t < QB) {
        int qq2 = t;
        double hv[NS]; int hj[NS];
#pragma unroll
        for (int s2 = 0; s2 < NS; ++s2) { hv[s2] = mv[(qq2 * NS + s2) * KK]; hj[s2] = 0; }
        int* op = idxout + ((size_t)(b * NN) + n0 + qq2) * KK;
#pragma unroll
        for (int r = 0; r < KK; ++r) {
            double best = -1e301; int bs = 0;
#pragma unroll
            for (int s2 = 0; s2 < NS; ++s2) {
                if (hv[s2] > best) { best = hv[s2]; bs = s2; }
            }
#pragma unroll
            for (int s2 = 0; s2 < NS; ++s2) {
                if (s2 == bs) {
                    op[r] = mi[(qq2 * NS + s2) * KK + hj[s2]];
                    hj[s2]++;
                    hv[s2] = (hj[s2] < KK) ? mv[(qq2 * NS + s2) * KK + hj[s2]] : -1e301;
                }
            }
        }
    }
}

// ---------------------------------------------------------------------------
// G/H precompute GEMM.
// ---------------------------------------------------------------------------
template <int C, int CO2, bool BF16OUT>
__global__ __launch_bounds__(256) void gh_kernel(const float* __restrict__ xin,
                                                 size_t xbstride,
                                                 const float* __restrict__ w1,
                                                 const float* __restrict__ b1,
                                                 void* __restrict__ Gout,
                                                 void* __restrict__ Hout)
{
    constexpr int TN = 128, TO = 64, KC = 16, NN = 512;
    __shared__ float xs[KC][TN];
    __shared__ float wls[KC][TO];
    __shared__ float wus[KC][TO];
    int t = threadIdx.x;
    constexpr int ntiles = NN / TN, otiles = CO2 / TO;
    int bid = blockIdx.x;
    int b = bid / (ntiles * otiles);
    int rem = bid % (ntiles * otiles);
    int n0 = (rem / otiles) * TN;
    int o0 = (rem % otiles) * TO;
    const float* xb = xin + (size_t)b * xbstride;

    int tn = t & 15, to = t >> 4;
    float accG[4][8], accH[4][8];
#pragma unroll
    for (int i = 0; i < 4; i++)
#pragma unroll
        for (int j = 0; j < 8; j++) { accG[i][j] = 0.f; accH[i][j] = 0.f; }

    for (int c0 = 0; c0 < C; c0 += KC) {
        __syncthreads();
        for (int e = t; e < KC * TN; e += 256) {
            int c = e >> 7, n = e & 127;
            xs[c][n] = xb[(size_t)(c0 + c) * NN + n0 + n];
        }
        for (int e = t; e < KC * TO; e += 256) {
            int o = e >> 4, c = e & 15;
            float wl = w1[(size_t)(o0 + o) * (2 * C) + c0 + c];
            float wr = w1[(size_t)(o0 + o) * (2 * C) + C + c0 + c];
            wls[c][o] = wl;
            wus[c][o] = wl + wr;
        }
        __syncthreads();
#pragma unroll 4
        for (int c = 0; c < KC; ++c) {
            float xv[8], wlv[4], wuv[4];
#pragma unroll
            for (int j = 0; j < 8; j++) xv[j] = xs[c][tn + j * 16];
#pragma unroll
            for (int i = 0; i < 4; i++) { wlv[i] = wls[c][to + i * 16]; wuv[i] = wus[c][to + i * 16]; }
#pragma unroll
            for (int i = 0; i < 4; i++)
#pragma unroll
                for (int j = 0; j < 8; j++) {
                    accG[i][j] += wuv[i] * xv[j];
                    accH[i][j] += wlv[i] * xv[j];
                }
        }
    }
#pragma unroll
    for (int i = 0; i < 4; i++) {
        int o = o0 + to + i * 16;
        float bb = b1[o];
#pragma unroll
        for (int j = 0; j < 8; j++) {
            int n = n0 + tn + j * 16;
            size_t off = ((size_t)b * NN + n) * CO2 + o;
            if constexpr (BF16OUT) {
                ((__hip_bfloat16*)Gout)[off] = __float2bfloat16(accG[i][j] + bb);
                ((__hip_bfloat16*)Hout)[off] = __float2bfloat16(accH[i][j]);
            } else {
                ((float*)Gout)[off] = accG[i][j] + bb;
                ((float*)Hout)[off] = accH[i][j];
            }
        }
    }
}

// ---------------------------------------------------------------------------
// Edge-conv pass over G/H (scalar fp32 path — used for stats + L2 passB).
// ---------------------------------------------------------------------------
template <int CO2, int KK, bool STATS, bool GHBF>
__global__ __launch_bounds__(CO2) void edge2_kernel(
    const void* __restrict__ Gin, const void* __restrict__ Hin,
    const int* __restrict__ idx,
    double* __restrict__ stats,
    const float* __restrict__ scsh, const float* __restrict__ w2,
    const float* __restrict__ b2,
    float* __restrict__ outp, size_t obstride, int tiles_per_block)
{
    constexpr int NN = 512, CCH = 16, TP = 32, TN = TP / KK;
    __shared__ float wtl[STATS ? 1 : CCH][STATS ? 1 : (CO2 + 1)];
    __shared__ float hn[STATS ? 1 : TP * CO2];
    __shared__ int   smidx[TP];
    int t = threadIdx.x;
    float ssum = 0.f, ssq = 0.f;

    for (int ti = 0; ti < tiles_per_block; ++ti) {
        int tileIdx = blockIdx.x * tiles_per_block + ti;
        int b = tileIdx / (NN / TN), nt = tileIdx % (NN / TN);
        int n0 = nt * TN;
        __syncthreads();
        if (t < TP) {
            int n = n0 + t / KK, kk = t % KK;
            smidx[t] = idx[((size_t)(b * NN) + n) * KK + kk];
        }
        __syncthreads();

        float h[TP];
#pragma unroll
        for (int p = 0; p < TP; p++) {
            int n = n0 + p / KK;
            int m = smidx[p];
            size_t go = ((size_t)b * NN + n) * CO2 + t;
            size_t ho = ((size_t)b * NN + m) * CO2 + t;
            float gv, hv;
            if constexpr (GHBF) {
                gv = __bfloat162float(((const __hip_bfloat16*)Gin)[go]);
                hv = __bfloat162float(((const __hip_bfloat16*)Hin)[ho]);
            } else {
                gv = ((const float*)Gin)[go];
                hv = ((const float*)Hin)[ho];
            }
            h[p] = gv - hv;
        }

        if constexpr (STATS) {
#pragma unroll
            for (int p = 0; p < TP; p++) { ssum += h[p]; ssq += h[p] * h[p]; }
        } else {
            float scv = scsh[t], shv = scsh[CO2 + t];
#pragma unroll
            for (int p = 0; p < TP; p++) {
                float v = h[p] * scv + shv;
                hn[p * CO2 + t] = (v >= 0.f) ? v : 0.2f * v;
            }
            for (int g = 0; g < 2; ++g) {
                float s[TP];
#pragma unroll
                for (int p = 0; p < TP; p++) s[p] = 0.f;
                for (int ch = 0; ch < CO2 / CCH; ++ch) {
                    int c0 = ch * CCH;
                    __syncthreads();
                    for (int e = t; e < CCH * CO2; e += CO2) {
                        int o = e / CCH, ci = e % CCH;
                        wtl[ci][o] = w2[((size_t)(g * CO2 + o)) * CO2 + c0 + ci];
                    }
                    __syncthreads();
#pragma unroll
                    for (int c4 = 0; c4 < CCH / 4; c4++) {
                        float a0 = wtl[c4 * 4][t], a1 = wtl[c4 * 4 + 1][t];
                        float a2 = wtl[c4 * 4 + 2][t], a3 = wtl[c4 * 4 + 3][t];
#pragma unroll
                        for (int p = 0; p < TP; p++) {
                            const float4 f = *(const float4*)&hn[p * CO2 + c0 + c4 * 4];
                            s[p] += a0 * f.x + a1 * f.y + a2 * f.z + a3 * f.w;
                        }
                    }
                }
                float bb2 = b2[g * CO2 + t];
#pragma unroll
                for (int nl = 0; nl < TN; ++nl) {
                    float mx = s[nl * KK];
#pragma unroll
                    for (int kk = 1; kk < KK; ++kk) mx = fmaxf(mx, s[nl * KK + kk]);
                    outp[(size_t)b * obstride + (size_t)(g * CO2 + t) * NN + n0 + nl] = mx + bb2;
                }
            }
        }
    }
    if constexpr (STATS) {
        atomicAdd(&stats[t], (double)ssum);
        atomicAdd(&stats[CO2 + t], (double)ssq);
    }
}

// ---------------------------------------------------------------------------
// L3 passB via MFMA.  Block = 8 points x 4 k = 32 pixel-cols, 4 waves.
// Phase 1: gather h = G-H (bf16), BN+leaky, bf16 -> LDS [32][264] (padded).
// Phase 2: D[512 o][32 px] = w3bf[512][256] x hn^T, 16x16x32 bf16 MFMA,
//          K = 256 (8 steps).  Wave wv owns o in [wv*128, wv*128+128).
// D layout (verified): col = lane&15 (pixel), row = (lane>>4)*4+reg (o).
// Max over the 4 k-slots = shfl_xor over lane bits 0,1; + bias; store.
// ---------------------------------------------------------------------------
__global__ __launch_bounds__(256) void edge3_mfma_kernel(
    const __hip_bfloat16* __restrict__ G, const __hip_bfloat16* __restrict__ H,
    const int* __restrict__ idx, const float* __restrict__ scsh,
    const __hip_bfloat16* __restrict__ w3bf, const float* __restrict__ b2,
    float* __restrict__ outp, size_t obstride)
{
    constexpr int NN = 512, CO2 = 256, TP = 32, PTS = 8, PITCH = 264;
    __shared__ __align__(16) unsigned short hnb[TP * PITCH];   // 16.5 KB bf16
    __shared__ int smidx[TP];
    int t = threadIdx.x;
    int b  = blockIdx.x >> 6;          // 64 point-groups per batch
    int pg = blockIdx.x & 63;
    int n0 = pg * PTS;

    if (t < TP) smidx[t] = idx[((size_t)(b * NN) + n0 + (t >> 2)) * 4 + (t & 3)];
    __syncthreads();

    {   // gather + BN + leaky -> bf16 LDS (thread t = channel t)
        float scv = scsh[t], shv = scsh[CO2 + t];
        const __hip_bfloat16* Gb = G + (size_t)b * NN * CO2;
        const __hip_bfloat16* Hb = H + (size_t)b * NN * CO2;
#pragma unroll
        for (int pt = 0; pt < PTS; ++pt) {
            float gv = __bfloat162float(Gb[(size_t)(n0 + pt) * CO2 + t]);
#pragma unroll
            for (int ks = 0; ks < 4; ++ks) {
                int p = pt * 4 + ks;
                int m = smidx[p];
                float hv = __bfloat162float(Hb[(size_t)m * CO2 + t]);
                float v = (gv - hv) * scv + shv;
                v = (v >= 0.f) ? v : 0.2f * v;
                __hip_bfloat16 bv = __float2bfloat16(v);
                hnb[p * PITCH + t] = *reinterpret_cast<unsigned short*>(&bv);
            }
        }
    }
    __syncthreads();

    int l = t & 63, wv = t >> 6;
    int lr = l & 15, lk = l >> 4;      // lr: A-row / B-col / D-col; lk: k-block
    f32x4 acc[8][2];
#pragma unroll
    for (int i = 0; i < 8; i++)
#pragma unroll
        for (int j = 0; j < 2; j++) acc[i][j] = (f32x4){0.f, 0.f, 0.f, 0.f};

    int o_wv = wv * 128;
    for (int kk = 0; kk < 8; ++kk) {
        int koff = kk * 32 + lk * 8;
        bf16x8 bfrag[2];
#pragma unroll
        for (int nt = 0; nt < 2; ++nt)
            bfrag[nt] = *reinterpret_cast<const bf16x8*>(&hnb[(nt * 16 + lr) * PITCH + koff]);
#pragma unroll
        for (int mt = 0; mt < 8; ++mt) {
            bf16x8 afrag = *reinterpret_cast<const bf16x8*>(
                &w3bf[(size_t)(o_wv + mt * 16 + lr) * CO2 + koff]);
#pragma unroll
            for (int nt = 0; nt < 2; ++nt)
                acc[mt][nt] = __builtin_amdgcn_mfma_f32_16x16x32_bf16(
                    afrag, bfrag[nt], acc[mt][nt], 0, 0, 0);
        }
    }

#pragma unroll
    for (int mt = 0; mt < 8; ++mt) {
#pragma unroll
        for (int nt = 0; nt < 2; ++nt) {
#pragma unroll
            for (int r = 0; r < 4; ++r) {
                float v = acc[mt][nt][r];
                v = fmaxf(v, __shfl_xor(v, 1));
                v = fmaxf(v, __shfl_xor(v, 2));
                if ((lr & 3) == 0) {
                    int o   = o_wv + mt * 16 + lk * 4 + r;
                    int pnt = n0 + nt * 4 + (lr >> 2);
                    outp[(size_t)b * obstride + (size_t)o * NN + pnt] = v + b2[o];
                }
            }
        }
    }
}

// ---------------------------------------------------------------------------
extern "C" void kernel_launch(void* const* d_in, const int* in_sizes, int n_in,
                              void* d_out, int out_size, void* d_ws, size_t ws_size,
                              hipStream_t stream)
{
    const float* x   = (const float*)d_in[0];
    const float* w1a = (const float*)d_in[1];
    const float* b1a = (const float*)d_in[2];
    const float* g1  = (const float*)d_in[3];
    const float* be1 = (const float*)d_in[4];
    const float* w1b = (const float*)d_in[5];
    const float* b1b = (const float*)d_in[6];
    const float* w2a = (const float*)d_in[7];
    const float* b2a = (const float*)d_in[8];
    const float* g2  = (const float*)d_in[9];
    const float* be2 = (const float*)d_in[10];
    const float* w2b = (const float*)d_in[11];
    const float* b2b = (const float*)d_in[12];
    const float* w3a = (const float*)d_in[13];
    const float* b3a = (const float*)d_in[14];
    const float* g3  = (const float*)d_in[15];
    const float* be3 = (const float*)d_in[16];
    const float* w3b = (const float*)d_in[17];
    const float* b3b = (const float*)d_in[18];

    float* out = (float*)d_out;
    float* fws = (float*)d_ws;
    int*    idx1   = (int*)(fws + OFF_IDX1);
    int*    idx2   = (int*)(fws + OFF_IDX2);
    int*    idx3   = (int*)(fws + OFF_IDX3);
    int*    fpsidx = (int*)(fws + OFF_FPS);
    double* st1 = (double*)(fws + OFF_ST);
    double* st2 = st1 + 64;
    double* st3 = st2 + 256;
    float*  ss1 = fws + OFF_SS1;
    float*  ss2 = fws + OFF_SS2;
    float*  ss3 = fws + OFF_SS3;
    double* nrm = (double*)(fws + OFF_NORM);
    float*  x1full = fws + OFF_X1F;
    float*  G2 = fws + OFF_X1F;
    float*  H2 = G2 + 2097152;
    __hip_bfloat16* G3 = (__hip_bfloat16*)(fws + OFF_X1F);
    __hip_bfloat16* H3 = (__hip_bfloat16*)(fws + OFF_X1F + 2097152);
    __hip_bfloat16* w3bf = (__hip_bfloat16*)(fws + OFF_W3BF);

    const size_t OB = 832 * 512;

    hipMemsetAsync(st1, 0, 832 * sizeof(double), stream);
    cvt_bf16_kernel<<<512, 256, 0, stream>>>(w3b, w3bf, 512 * 256);

    // ---- layer 1 ----
    knn3d3_kernel<<<1024, 256, 0, stream>>>(x, idx1);
    stats1_kernel<<<256, 256, 0, stream>>>(x, idx1, w1a, b1a, st1);
    finalize_kernel<<<1, 256, 0, stream>>>(st1, g1, be1, ss1, 32, 1.0 / 1048576.0);
    passB1_kernel<<<4096, 256, 0, stream>>>(x, idx1, w1a, b1a, ss1, w1b, b1b, x1full);

    // ---- fps + gather ----
    fps2_kernel<<<32, 256, 0, stream>>>(x, fpsidx);
    gather_kernel<<<4096, 256, 0, stream>>>(x1full, fpsidx, out);
    // x1full dead from here; region reused for G2/H2 then G3/H3.

    // ---- layer 2 (input = out channels [0,64)) ----
    norms_kernel<64><<<64, 256, 0, stream>>>(out, OB, nrm);
    knn_feat2_kernel<64, 8><<<1024, 256, 0, stream>>>(out, OB, nrm, idx2);
    gh_kernel<64, 128, false><<<256, 256, 0, stream>>>(out, OB, w2a, b2a, G2, H2);
    edge2_kernel<128, 8, true, false><<<512, 128, 0, stream>>>(
        G2, H2, idx2, st2, nullptr, nullptr, nullptr, nullptr, 0, 8);
    finalize_kernel<<<1, 256, 0, stream>>>(st2, g2, be2, ss2, 128, 1.0 / 131072.0);
    edge2_kernel<128, 8, false, false><<<4096, 128, 0, stream>>>(
        G2, H2, idx2, nullptr, ss2, w2b, b2b, out + 64 * 512, OB, 1);

    // ---- layer 3 (input = out channels [64,320)) ----
    norms_kernel<256><<<64, 256, 0, stream>>>(out + 64 * 512, OB, nrm);
    knn_feat2_kernel<256, 4><<<1024, 256, 0, stream>>>(out + 64 * 512, OB, nrm, idx3);
    gh_kernel<256, 256, true><<<512, 256, 0, stream>>>(out + 64 * 512, OB, w3a, b3a, G3, H3);
    edge2_kernel<256, 4, true, true><<<512, 256, 0, stream>>>(
        G3, H3, idx3, st3, nullptr, nullptr, nullptr, nullptr, 0, 4);
    finalize_kernel<<<1, 256, 0, stream>>>(st3, g3, be3, ss3, 256, 1.0 / 65536.0);
    edge3_mfma_kernel<<<2048, 256, 0, stream>>>(
        G3, H3, idx3, ss3, w3bf, b3b, out + 320 * 512, OB);
}